// Round 13
// baseline (59.822 us; speedup 1.0000x reference)
//
#include <hip/hip_runtime.h>
#include <hip/hip_bf16.h>

// BQQ dims: P=2, J=32, K=32, M=128, L=16, N=128; B=512; in=kn=4096; out=jm=4096
typedef __attribute__((ext_vector_type(4))) float f32x4;
typedef __attribute__((ext_vector_type(8))) short bf16x8;
typedef __attribute__((ext_vector_type(4))) unsigned int u32x4;

#define GLOBAL_AS __attribute__((address_space(1)))
#define LDS_AS __attribute__((address_space(3)))

static __device__ __forceinline__ unsigned short f2bf(float f) {
  __hip_bfloat16 h = __float2bfloat16(f);
  return __builtin_bit_cast(unsigned short, h);
}
static __device__ __forceinline__ float bf2f(unsigned short u) {
  unsigned int v = ((unsigned int)u) << 16;
  return __builtin_bit_cast(float, v);
}
static __device__ __forceinline__ void load_lds16(const void* g, void* l) {
  __builtin_amdgcn_global_load_lds((GLOBAL_AS void*)g, (LDS_AS void*)l, 16, 0, 0);
}

// ---------------- 1) per-block min/max of input (2M f32), 256 blocks ----------------
__global__ __launch_bounds__(256) void k_minmax_part(const float* __restrict__ x,
                                                     float* __restrict__ part) {
  int tid = blockIdx.x * 256 + threadIdx.x;
  const float4* xv = (const float4*)x;
  float mn = 3.4e38f, mx = -3.4e38f;
#pragma unroll
  for (int rep = 0; rep < 8; ++rep) {
    float4 v = xv[tid + rep * 65536];
    mn = fminf(mn, fminf(fminf(v.x, v.y), fminf(v.z, v.w)));
    mx = fmaxf(mx, fmaxf(fmaxf(v.x, v.y), fmaxf(v.z, v.w)));
  }
#pragma unroll
  for (int o = 32; o > 0; o >>= 1) {
    mn = fminf(mn, __shfl_down(mn, o));
    mx = fmaxf(mx, __shfl_down(mx, o));
  }
  __shared__ float smn[4], smx[4];
  int lane = threadIdx.x & 63, w = threadIdx.x >> 6;
  if (lane == 0) { smn[w] = mn; smx[w] = mx; }
  __syncthreads();
  if (threadIdx.x == 0) {
    mn = fminf(fminf(smn[0], smn[1]), fminf(smn[2], smn[3]));
    mx = fmaxf(fmaxf(smx[0], smx[1]), fmaxf(smx[2], smx[3]));
    part[2 * blockIdx.x] = mn;
    part[2 * blockIdx.x + 1] = mx;
  }
}

// ---------------- 2) fused: blocks 0..1023 = build W (MFMA); 1024..3071 = quantize ----------------
__global__ __launch_bounds__(256) void k_fused(const float* __restrict__ x,
                                               const float* __restrict__ part,
                                               const float* __restrict__ Ysg,
                                               const float* __restrict__ Zsg,
                                               const float* __restrict__ Ysc,
                                               const float* __restrict__ Zsc,
                                               const float* __restrict__ Acoef,
                                               float* __restrict__ scl,
                                               unsigned short* __restrict__ xq,
                                               unsigned short* __restrict__ W) {
  const int t = threadIdx.x;
  if (blockIdx.x < 1024) {
    // ---- build_w (MFMA) ----
    const int jk = blockIdx.x;  // j*32+k
    __shared__ unsigned short Yb[2 * 128 * 24];  // [p*128+m][24] halves; data in [0..16)
    __shared__ unsigned short Zb[128 * 36];      // [n][36] halves; data pl in [0..32)
    __shared__ float B1p[2][128];
    __shared__ float C1[128];
    float cf0[2], cf2[2], cf4[2];
    float Dv;
    {
      float ys0 = Ysc[jk], zs0 = Zsc[jk], ys1 = Ysc[1024 + jk], zs1 = Zsc[1024 + jk];
      const float* A0p = Acoef + (size_t)jk * 4;
      const float* A1p = Acoef + (size_t)(1024 + jk) * 4;
      cf0[0] = A0p[0] * ys0 * zs0; cf0[1] = A1p[0] * ys1 * zs1;
      cf2[0] = A0p[1] * ys0;       cf2[1] = A1p[1] * ys1;
      cf4[0] = A0p[2] * zs0;       cf4[1] = A1p[2] * zs1;
      Dv = A0p[3] + A1p[3];
    }
#pragma unroll
    for (int rep = 0; rep < 4; ++rep) {
      int q = rep * 256 + t;
      int l0 = (q & 3) * 4, m = (q >> 2) & 127, p = q >> 9;
      float4 v = *(const float4*)(Ysg + (size_t)(p * 1024 + jk) * 2048 + m * 16 + l0);
      float s4 = v.x + v.y + v.z + v.w;
      s4 += __shfl_xor(s4, 1);
      s4 += __shfl_xor(s4, 2);
      if ((t & 3) == 0) B1p[p][m] = s4;
      float c0 = cf0[p];
      ushort4 o = make_ushort4(f2bf(c0 * v.x), f2bf(c0 * v.y), f2bf(c0 * v.z), f2bf(c0 * v.w));
      *(ushort4*)&Yb[(p * 128 + m) * 24 + l0] = o;
    }
#pragma unroll
    for (int rep = 0; rep < 4; ++rep) {
      int q = rep * 256 + t;
      int n0 = (q & 31) * 4, l = (q >> 5) & 15, p = q >> 9;
      float4 v = *(const float4*)(Zsg + (size_t)(p * 1024 + jk) * 2048 + l * 128 + n0);
      int pl = p * 16 + l;
      Zb[(n0 + 0) * 36 + pl] = f2bf(v.x);
      Zb[(n0 + 1) * 36 + pl] = f2bf(v.y);
      Zb[(n0 + 2) * 36 + pl] = f2bf(v.z);
      Zb[(n0 + 3) * 36 + pl] = f2bf(v.w);
    }
    __syncthreads();
    if (t < 128) {
      float s0 = 0.f, s1 = 0.f;
#pragma unroll
      for (int l = 0; l < 16; ++l) {
        s0 += bf2f(Zb[t * 36 + l]);
        s1 += bf2f(Zb[t * 36 + 16 + l]);
      }
      C1[t] = cf4[0] * s0 + cf4[1] * s1;
    }
    __syncthreads();
    const int lane = t & 63, wid = t >> 6;
    const int wm = wid >> 1, wn = wid & 1;
    const int grp = lane >> 4;
    bf16x8 af[4], bfr[4];
#pragma unroll
    for (int fm = 0; fm < 4; ++fm) {
      int m = wm * 64 + fm * 16 + (lane & 15);
      af[fm] = *(const bf16x8*)((const char*)Yb + ((grp >> 1) * 128 + m) * 48 + (grp & 1) * 16);
    }
#pragma unroll
    for (int fn = 0; fn < 4; ++fn) {
      int n = wn * 64 + fn * 16 + (lane & 15);
      const char* zp = (const char*)Zb + n * 72 + grp * 16;
      uint2 z0 = *(const uint2*)zp;
      uint2 z1 = *(const uint2*)(zp + 8);
      u32x4 zw; zw[0] = z0.x; zw[1] = z0.y; zw[2] = z1.x; zw[3] = z1.y;
      bfr[fn] = __builtin_bit_cast(bf16x8, zw);
    }
    f32x4 acc[4][4];
#pragma unroll
    for (int fm = 0; fm < 4; ++fm)
#pragma unroll
      for (int fn = 0; fn < 4; ++fn)
        acc[fm][fn] = __builtin_amdgcn_mfma_f32_16x16x32_bf16(af[fm], bfr[fn], (f32x4)(0.f), 0, 0, 0);
    const int j = jk >> 5, k = jk & 31;
    float c1v[4];
#pragma unroll
    for (int fn = 0; fn < 4; ++fn) c1v[fn] = C1[wn * 64 + fn * 16 + (lane & 15)];
#pragma unroll
    for (int fm = 0; fm < 4; ++fm) {
#pragma unroll
      for (int i = 0; i < 4; ++i) {
        int row = wm * 64 + fm * 16 + (grp)*4 + i;
        float b1v = cf2[0] * B1p[0][row] + cf2[1] * B1p[1][row] + Dv;
        size_t rowoff = (size_t)(j * 128 + row) * 4096 + (size_t)(k * 128);
#pragma unroll
        for (int fn = 0; fn < 4; ++fn) {
          int col = wn * 64 + fn * 16 + (lane & 15);
          W[rowoff + col] = f2bf(acc[fm][fn][i] + b1v + c1v[fn]);
        }
      }
    }
  } else {
    // ---- quantize ----
    const int qb = blockIdx.x - 1024;
    float2 v2 = ((const float2*)part)[t];
    float mn = v2.x, mx = v2.y;
#pragma unroll
    for (int o = 32; o > 0; o >>= 1) {
      mn = fminf(mn, __shfl_down(mn, o));
      mx = fmaxf(mx, __shfl_down(mx, o));
    }
    __shared__ float smn2[4], smx2[4], ssc[1];
    int lane = t & 63, w = t >> 6;
    if (lane == 0) { smn2[w] = mn; smx2[w] = mx; }
    __syncthreads();
    if (t == 0) {
      mn = fminf(fminf(smn2[0], smn2[1]), fminf(smn2[2], smn2[3]));
      mx = fmaxf(fmaxf(smx2[0], smx2[1]), fmaxf(smx2[2], smx2[3]));
      ssc[0] = fmaxf((mx - mn) / 254.0f, 1e-8f);
      if (qb == 0) scl[0] = ssc[0];
    }
    __syncthreads();
    const float s = ssc[0];
    int i = qb * 256 + t;
    float4 v = ((const float4*)x)[i];
    float a = fminf(fmaxf(rintf(v.x / s), -127.f), 127.f);
    float b = fminf(fmaxf(rintf(v.y / s), -127.f), 127.f);
    float c = fminf(fmaxf(rintf(v.z / s), -127.f), 127.f);
    float d = fminf(fmaxf(rintf(v.w / s), -127.f), 127.f);
    ((ushort4*)xq)[i] = make_ushort4(f2bf(a), f2bf(b), f2bf(c), f2bf(d));
  }
}

// ---------------- 3) GEMM split-K8: BM=256,BN=256,BK=32; ring-4, stage-ahead-3 ----------------
// Grid 256 = 8(sk==XCD) x 2(bm) x 16(bn); 8 waves 2x4, wave 128x64, 16 K-iters.
// Per iter: 4 loads/wave, vmcnt(12) -> tile t landed with 3 tiles (12 loads) in
// flight across barriers; 12 ds_read_b128; 32 MFMA in a setprio cluster.
// 64B LDS rows: 4-slot swizzle slot=(g+(r>>1))&3 -> 2-way ds_read aliasing (free).
// Swizzle applied to GLOBAL source col; gload_lds dest stays linear (rule #21).
__global__ __launch_bounds__(512) void k_gemm(const unsigned short* __restrict__ Xq,
                                              const unsigned short* __restrict__ W,
                                              unsigned short* __restrict__ P) {
  __shared__ unsigned short Al[4][256 * 32];  // 4 x 16KB
  __shared__ unsigned short Bl[4][256 * 32];  // 4 x 16KB
  const int t = threadIdx.x, lane = t & 63, wid = t >> 6;  // wid 0..7
  const int wg = (blockIdx.x & 7) * 32 + (blockIdx.x >> 3);  // bijective, 256%8==0
  const int sk = wg >> 5;        // 0..7 == XCD id -> W K-panel 4MB = its L2
  const int bm = (wg >> 4) & 1;  // 0..1
  const int bn = wg & 15;        // 0..15
  const int wm = wid >> 2, wn = wid & 3;  // wave tile 128x64 (2x4 waves)
  const int kbase = sk * 512;
  f32x4 acc[8][4];
#pragma unroll
  for (int a = 0; a < 8; ++a)
#pragma unroll
    for (int b = 0; b < 4; ++b) acc[a][b] = (f32x4)(0.f);

  const int srow = lane >> 2;   // row-in-chunk 0..15
  const int sphys = lane & 3;   // physical 16B slot 0..3

  auto STAGE = [&](int buf, int kt) {
    const int k0 = kbase + kt * 32;
#pragma unroll
    for (int c2 = 0; c2 < 2; ++c2) {
      int chunk = wid * 2 + c2;
      int r = chunk * 16 + srow;
      int g = (sphys - (r >> 1)) & 3;  // logical K-seg stored in this phys slot
      load_lds16(Xq + ((size_t)(bm * 256 + r) << 12) + k0 + g * 8, &Al[buf][chunk * 512]);
    }
#pragma unroll
    for (int c2 = 0; c2 < 2; ++c2) {
      int chunk = wid * 2 + c2;
      int r = chunk * 16 + srow;
      int g = (sphys - (r >> 1)) & 3;
      load_lds16(W + ((size_t)(bn * 256 + r) << 12) + k0 + g * 8, &Bl[buf][chunk * 512]);
    }
  };

  // prologue: 3 tiles (12 loads/wave) in flight
  STAGE(0, 0);
  STAGE(1, 1);
  STAGE(2, 2);
  for (int it = 0; it < 16; ++it) {
    STAGE((it + 3) & 3, (it + 3) & 15);  // it>=13 restages kt 0..2 (dummy, never read)
    __builtin_amdgcn_sched_barrier(0);
    asm volatile("s_waitcnt vmcnt(12)" ::: "memory");  // tile it landed; 12 in flight
    __builtin_amdgcn_sched_barrier(0);
    __builtin_amdgcn_s_barrier();                      // buf[it&3] ready for all waves
    __builtin_amdgcn_sched_barrier(0);
    const int cur = it & 3;
    bf16x8 af[8], bfr[4];
#pragma unroll
    for (int fm = 0; fm < 8; ++fm) {
      int r = wm * 128 + fm * 16 + (lane & 15);
      int s = ((lane >> 4) + (r >> 1)) & 3;
      af[fm] = *(const bf16x8*)((const char*)&Al[cur][0] + r * 64 + s * 16);
    }
#pragma unroll
    for (int fn = 0; fn < 4; ++fn) {
      int r = wn * 64 + fn * 16 + (lane & 15);
      int s = ((lane >> 4) + (r >> 1)) & 3;
      bfr[fn] = *(const bf16x8*)((const char*)&Bl[cur][0] + r * 64 + s * 16);
    }
    __builtin_amdgcn_sched_barrier(0);
    __builtin_amdgcn_s_setprio(1);
#pragma unroll
    for (int fm = 0; fm < 8; ++fm)
#pragma unroll
      for (int fn = 0; fn < 4; ++fn)
        acc[fm][fn] = __builtin_amdgcn_mfma_f32_16x16x32_bf16(af[fm], bfr[fn], acc[fm][fn], 0, 0, 0);
    __builtin_amdgcn_s_setprio(0);
    __builtin_amdgcn_sched_barrier(0);
    __builtin_amdgcn_s_barrier();  // reads of cur done before it+4 overwrites it
  }

  // register-native coalesced bf16 partial store (512B contiguous per inst)
  unsigned short* Pk = P + (size_t)sk * 2097152;
  const int blkL = bm * 16 + bn;  // 0..31
#pragma unroll
  for (int fm = 0; fm < 8; ++fm) {
#pragma unroll
    for (int fn = 0; fn < 4; ++fn) {
      int idx = (((blkL * 8 + wid) * 32 + fm * 4 + fn) * 64) + lane;
      ushort4 o = make_ushort4(f2bf(acc[fm][fn][0]), f2bf(acc[fm][fn][1]),
                               f2bf(acc[fm][fn][2]), f2bf(acc[fm][fn][3]));
      ((ushort4*)Pk)[idx] = o;
    }
  }
}

// ---------------- 4) epilogue: out = (sum of 8 native-layout partials) * s + bias ----------------
__global__ __launch_bounds__(256) void k_epi(float* __restrict__ out,
                                             const unsigned short* __restrict__ P,
                                             const float* __restrict__ scl,
                                             const float* __restrict__ bias) {
  int g = blockIdx.x * 256 + threadIdx.x;  // 524288 threads, 4 elems each
  const int lane = g & 63;
  const int ff = (g >> 6) & 31;
  const int fn = ff & 3, fm = ff >> 2;
  const int wid = (g >> 11) & 7;
  const int blkL = g >> 14;  // 0..31
  const int bm = blkL >> 4, bn = blkL & 15;
  const int wm = wid >> 2, wn = wid & 3;
  const int row0 = bm * 256 + wm * 128 + fm * 16 + ((lane >> 4) << 2);
  const int col = bn * 256 + wn * 64 + fn * 16 + (lane & 15);
  const float s = scl[0];
  const float bv = bias[col];
  float sum[4] = {0.f, 0.f, 0.f, 0.f};
#pragma unroll
  for (int k = 0; k < 8; ++k) {
    ushort4 p = ((const ushort4*)(P + (size_t)k * 2097152))[g];
    sum[0] += bf2f(p.x); sum[1] += bf2f(p.y); sum[2] += bf2f(p.z); sum[3] += bf2f(p.w);
  }
#pragma unroll
  for (int i = 0; i < 4; ++i) out[(size_t)(row0 + i) * 4096 + col] = sum[i] * s + bv;
}

// ---------------- fallback GEMM (used if ws too small for partials) ----------------
__global__ __launch_bounds__(512) void k_gemm_fb(const unsigned short* __restrict__ Xq,
                                                 const unsigned short* __restrict__ W,
                                                 const float* __restrict__ scl,
                                                 const float* __restrict__ bias,
                                                 float* __restrict__ out) {
  __shared__ unsigned short Al[4][128 * 64];
  __shared__ unsigned short Bl[4][64 * 64];
  const int t = threadIdx.x, lane = t & 63, wid = t >> 6;
  const int wg = (blockIdx.x & 7) * 32 + (blockIdx.x >> 3);
  const int bm = wg & 3;
  const int bn = wg >> 2;
  const int wm = wid >> 1, wn = wid & 1;
  f32x4 acc[2][2];
#pragma unroll
  for (int a = 0; a < 2; ++a)
#pragma unroll
    for (int b = 0; b < 2; ++b) acc[a][b] = (f32x4)(0.f);
  const int lr = lane >> 3;
  const int lcb = (lane & 7) * 16;
  auto STAGE = [&](int buf, int kt) {
    const int k0 = kt * 64;
#pragma unroll
    for (int c = 0; c < 2; ++c) {
      int chunk = wid * 2 + c;
      int r = chunk * 8 + lr;
      int colb = lcb ^ ((r & 7) << 4);
      load_lds16(Xq + ((size_t)(bm * 128 + r) << 12) + k0 + (colb >> 1), &Al[buf][chunk * 512]);
    }
    {
      int r = wid * 8 + lr;
      int colb = lcb ^ ((r & 7) << 4);
      load_lds16(W + ((size_t)(bn * 64 + r) << 12) + k0 + (colb >> 1), &Bl[buf][wid * 512]);
    }
  };
  auto COMPUTE = [&](int buf) {
#pragma unroll
    for (int ks = 0; ks < 2; ++ks) {
      bf16x8 af[2], bfr[2];
#pragma unroll
      for (int fm = 0; fm < 2; ++fm) {
        int r = wm * 32 + fm * 16 + (lane & 15);
        int colb = (ks * 64 + ((lane >> 4) * 16)) ^ ((r & 7) << 4);
        af[fm] = *(const bf16x8*)((const char*)&Al[buf][0] + r * 128 + colb);
      }
#pragma unroll
      for (int fn = 0; fn < 2; ++fn) {
        int r = wn * 32 + fn * 16 + (lane & 15);
        int colb = (ks * 64 + ((lane >> 4) * 16)) ^ ((r & 7) << 4);
        bfr[fn] = *(const bf16x8*)((const char*)&Bl[buf][0] + r * 128 + colb);
      }
#pragma unroll
      for (int fm = 0; fm < 2; ++fm)
#pragma unroll
        for (int fn = 0; fn < 2; ++fn)
          acc[fm][fn] = __builtin_amdgcn_mfma_f32_16x16x32_bf16(af[fm], bfr[fn], acc[fm][fn], 0, 0, 0);
    }
  };
  STAGE(0, 0); STAGE(1, 1); STAGE(2, 2);
  for (int t64 = 0; t64 < 64; ++t64) {
    STAGE((t64 + 3) & 3, (t64 + 3) & 63);
    __builtin_amdgcn_sched_barrier(0);
    asm volatile("s_waitcnt vmcnt(9)" ::: "memory");
    __builtin_amdgcn_sched_barrier(0);
    __builtin_amdgcn_s_barrier();
    __builtin_amdgcn_sched_barrier(0);
    COMPUTE(t64 & 3);
    __builtin_amdgcn_sched_barrier(0);
    __builtin_amdgcn_s_barrier();
  }
  const float s = scl[0];
#pragma unroll
  for (int fn = 0; fn < 2; ++fn) {
    int col = bn * 64 + wn * 32 + fn * 16 + (lane & 15);
    float bv = bias[col];
#pragma unroll
    for (int fm = 0; fm < 2; ++fm) {
#pragma unroll
      for (int i = 0; i < 4; ++i) {
        int row = bm * 128 + wm * 32 + fm * 16 + (lane >> 4) * 4 + i;
        out[(size_t)row * 4096 + col] = acc[fm][fn][i] * s + bv;
      }
    }
  }
}

extern "C" void kernel_launch(void* const* d_in, const int* in_sizes, int n_in,
                              void* d_out, int out_size, void* d_ws, size_t ws_size,
                              hipStream_t stream) {
  const float* x    = (const float*)d_in[0];  // (1,512,4096)
  const float* Ysg  = (const float*)d_in[1];  // (2,32,32,128,16)
  const float* Zsg  = (const float*)d_in[2];  // (2,32,32,16,128)
  const float* Ysc  = (const float*)d_in[3];  // (2,32,32)
  const float* Zsc  = (const float*)d_in[4];  // (2,32,32)
  const float* A    = (const float*)d_in[5];  // (2,32,32,4)
  const float* bias = (const float*)d_in[6];  // (4096,)
  float* out = (float*)d_out;

  char* ws = (char*)d_ws;
  float* scl  = (float*)ws;                  // [0] act_scale
  float* part = (float*)(ws + 256);          // 512 f32 partials
  unsigned short* Xq = (unsigned short*)(ws + 65536);                    // 4MB bf16
  unsigned short* W  = (unsigned short*)(ws + 65536 + (size_t)4194304);  // 32MB bf16
  unsigned short* P  = (unsigned short*)(ws + 65536 + (size_t)4194304 + (size_t)33554432);  // 32MB bf16 partials (8 slices)

  k_minmax_part<<<dim3(256), dim3(256), 0, stream>>>(x, part);
  k_fused<<<dim3(3072), dim3(256), 0, stream>>>(x, part, Ysg, Zsg, Ysc, Zsc, A, scl, Xq, W);
  if (ws_size >= (size_t)65536 + 4194304 + 33554432 + 33554432) {
    k_gemm<<<dim3(256), dim3(512), 0, stream>>>(Xq, W, P);
    k_epi<<<dim3(2048), dim3(256), 0, stream>>>(out, P, scl, bias);
  } else {
    k_gemm_fb<<<dim3(256), dim3(512), 0, stream>>>(Xq, W, scl, bias, out);
  }
}

// Round 14
// 57.966 us; speedup vs baseline: 1.0320x; 1.0320x over previous
//
#include <hip/hip_runtime.h>
#include <hip/hip_bf16.h>

// BQQ dims: P=2, J=32, K=32, M=128, L=16, N=128; B=512; in=kn=4096; out=jm=4096
typedef __attribute__((ext_vector_type(4))) float f32x4;
typedef __attribute__((ext_vector_type(8))) short bf16x8;
typedef __attribute__((ext_vector_type(4))) unsigned int u32x4;

#define GLOBAL_AS __attribute__((address_space(1)))
#define LDS_AS __attribute__((address_space(3)))

static __device__ __forceinline__ unsigned short f2bf(float f) {
  __hip_bfloat16 h = __float2bfloat16(f);
  return __builtin_bit_cast(unsigned short, h);
}
static __device__ __forceinline__ float bf2f(unsigned short u) {
  unsigned int v = ((unsigned int)u) << 16;
  return __builtin_bit_cast(float, v);
}
static __device__ __forceinline__ void load_lds16(const void* g, void* l) {
  __builtin_amdgcn_global_load_lds((GLOBAL_AS void*)g, (LDS_AS void*)l, 16, 0, 0);
}

// ---------------- 1) per-block min/max of input (2M f32), 256 blocks ----------------
__global__ __launch_bounds__(256) void k_minmax_part(const float* __restrict__ x,
                                                     float* __restrict__ part) {
  int tid = blockIdx.x * 256 + threadIdx.x;
  const float4* xv = (const float4*)x;
  float mn = 3.4e38f, mx = -3.4e38f;
#pragma unroll
  for (int rep = 0; rep < 8; ++rep) {
    float4 v = xv[tid + rep * 65536];
    mn = fminf(mn, fminf(fminf(v.x, v.y), fminf(v.z, v.w)));
    mx = fmaxf(mx, fmaxf(fmaxf(v.x, v.y), fmaxf(v.z, v.w)));
  }
#pragma unroll
  for (int o = 32; o > 0; o >>= 1) {
    mn = fminf(mn, __shfl_down(mn, o));
    mx = fmaxf(mx, __shfl_down(mx, o));
  }
  __shared__ float smn[4], smx[4];
  int lane = threadIdx.x & 63, w = threadIdx.x >> 6;
  if (lane == 0) { smn[w] = mn; smx[w] = mx; }
  __syncthreads();
  if (threadIdx.x == 0) {
    mn = fminf(fminf(smn[0], smn[1]), fminf(smn[2], smn[3]));
    mx = fmaxf(fmaxf(smx[0], smx[1]), fmaxf(smx[2], smx[3]));
    part[2 * blockIdx.x] = mn;
    part[2 * blockIdx.x + 1] = mx;
  }
}

// ---------------- 2) fused: blocks 0..1023 = build W (MFMA); 1024..3071 = quantize ----------------
__global__ __launch_bounds__(256) void k_fused(const float* __restrict__ x,
                                               const float* __restrict__ part,
                                               const float* __restrict__ Ysg,
                                               const float* __restrict__ Zsg,
                                               const float* __restrict__ Ysc,
                                               const float* __restrict__ Zsc,
                                               const float* __restrict__ Acoef,
                                               float* __restrict__ scl,
                                               unsigned short* __restrict__ xq,
                                               unsigned short* __restrict__ W) {
  const int t = threadIdx.x;
  if (blockIdx.x < 1024) {
    // ---- build_w (MFMA) ----
    const int jk = blockIdx.x;  // j*32+k
    __shared__ unsigned short Yb[2 * 128 * 24];  // [p*128+m][24] halves; data in [0..16)
    __shared__ unsigned short Zb[128 * 36];      // [n][36] halves; data pl in [0..32)
    __shared__ float B1p[2][128];
    __shared__ float C1[128];
    float cf0[2], cf2[2], cf4[2];
    float Dv;
    {
      float ys0 = Ysc[jk], zs0 = Zsc[jk], ys1 = Ysc[1024 + jk], zs1 = Zsc[1024 + jk];
      const float* A0p = Acoef + (size_t)jk * 4;
      const float* A1p = Acoef + (size_t)(1024 + jk) * 4;
      cf0[0] = A0p[0] * ys0 * zs0; cf0[1] = A1p[0] * ys1 * zs1;
      cf2[0] = A0p[1] * ys0;       cf2[1] = A1p[1] * ys1;
      cf4[0] = A0p[2] * zs0;       cf4[1] = A1p[2] * zs1;
      Dv = A0p[3] + A1p[3];
    }
#pragma unroll
    for (int rep = 0; rep < 4; ++rep) {
      int q = rep * 256 + t;
      int l0 = (q & 3) * 4, m = (q >> 2) & 127, p = q >> 9;
      float4 v = *(const float4*)(Ysg + (size_t)(p * 1024 + jk) * 2048 + m * 16 + l0);
      float s4 = v.x + v.y + v.z + v.w;
      s4 += __shfl_xor(s4, 1);
      s4 += __shfl_xor(s4, 2);
      if ((t & 3) == 0) B1p[p][m] = s4;
      float c0 = cf0[p];
      ushort4 o = make_ushort4(f2bf(c0 * v.x), f2bf(c0 * v.y), f2bf(c0 * v.z), f2bf(c0 * v.w));
      *(ushort4*)&Yb[(p * 128 + m) * 24 + l0] = o;
    }
#pragma unroll
    for (int rep = 0; rep < 4; ++rep) {
      int q = rep * 256 + t;
      int n0 = (q & 31) * 4, l = (q >> 5) & 15, p = q >> 9;
      float4 v = *(const float4*)(Zsg + (size_t)(p * 1024 + jk) * 2048 + l * 128 + n0);
      int pl = p * 16 + l;
      Zb[(n0 + 0) * 36 + pl] = f2bf(v.x);
      Zb[(n0 + 1) * 36 + pl] = f2bf(v.y);
      Zb[(n0 + 2) * 36 + pl] = f2bf(v.z);
      Zb[(n0 + 3) * 36 + pl] = f2bf(v.w);
    }
    __syncthreads();
    if (t < 128) {
      float s0 = 0.f, s1 = 0.f;
#pragma unroll
      for (int l = 0; l < 16; ++l) {
        s0 += bf2f(Zb[t * 36 + l]);
        s1 += bf2f(Zb[t * 36 + 16 + l]);
      }
      C1[t] = cf4[0] * s0 + cf4[1] * s1;
    }
    __syncthreads();
    const int lane = t & 63, wid = t >> 6;
    const int wm = wid >> 1, wn = wid & 1;
    const int grp = lane >> 4;
    bf16x8 af[4], bfr[4];
#pragma unroll
    for (int fm = 0; fm < 4; ++fm) {
      int m = wm * 64 + fm * 16 + (lane & 15);
      af[fm] = *(const bf16x8*)((const char*)Yb + ((grp >> 1) * 128 + m) * 48 + (grp & 1) * 16);
    }
#pragma unroll
    for (int fn = 0; fn < 4; ++fn) {
      int n = wn * 64 + fn * 16 + (lane & 15);
      const char* zp = (const char*)Zb + n * 72 + grp * 16;
      uint2 z0 = *(const uint2*)zp;
      uint2 z1 = *(const uint2*)(zp + 8);
      u32x4 zw; zw[0] = z0.x; zw[1] = z0.y; zw[2] = z1.x; zw[3] = z1.y;
      bfr[fn] = __builtin_bit_cast(bf16x8, zw);
    }
    f32x4 acc[4][4];
#pragma unroll
    for (int fm = 0; fm < 4; ++fm)
#pragma unroll
      for (int fn = 0; fn < 4; ++fn)
        acc[fm][fn] = __builtin_amdgcn_mfma_f32_16x16x32_bf16(af[fm], bfr[fn], (f32x4)(0.f), 0, 0, 0);
    const int j = jk >> 5, k = jk & 31;
    float c1v[4];
#pragma unroll
    for (int fn = 0; fn < 4; ++fn) c1v[fn] = C1[wn * 64 + fn * 16 + (lane & 15)];
#pragma unroll
    for (int fm = 0; fm < 4; ++fm) {
#pragma unroll
      for (int i = 0; i < 4; ++i) {
        int row = wm * 64 + fm * 16 + (grp)*4 + i;
        float b1v = cf2[0] * B1p[0][row] + cf2[1] * B1p[1][row] + Dv;
        size_t rowoff = (size_t)(j * 128 + row) * 4096 + (size_t)(k * 128);
#pragma unroll
        for (int fn = 0; fn < 4; ++fn) {
          int col = wn * 64 + fn * 16 + (lane & 15);
          W[rowoff + col] = f2bf(acc[fm][fn][i] + b1v + c1v[fn]);
        }
      }
    }
  } else {
    // ---- quantize ----
    const int qb = blockIdx.x - 1024;
    float2 v2 = ((const float2*)part)[t];
    float mn = v2.x, mx = v2.y;
#pragma unroll
    for (int o = 32; o > 0; o >>= 1) {
      mn = fminf(mn, __shfl_down(mn, o));
      mx = fmaxf(mx, __shfl_down(mx, o));
    }
    __shared__ float smn2[4], smx2[4], ssc[1];
    int lane = t & 63, w = t >> 6;
    if (lane == 0) { smn2[w] = mn; smx2[w] = mx; }
    __syncthreads();
    if (t == 0) {
      mn = fminf(fminf(smn2[0], smn2[1]), fminf(smn2[2], smn2[3]));
      mx = fmaxf(fmaxf(smx2[0], smx2[1]), fmaxf(smx2[2], smx2[3]));
      ssc[0] = fmaxf((mx - mn) / 254.0f, 1e-8f);
      if (qb == 0) scl[0] = ssc[0];
    }
    __syncthreads();
    const float s = ssc[0];
    int i = qb * 256 + t;
    float4 v = ((const float4*)x)[i];
    float a = fminf(fmaxf(rintf(v.x / s), -127.f), 127.f);
    float b = fminf(fmaxf(rintf(v.y / s), -127.f), 127.f);
    float c = fminf(fmaxf(rintf(v.z / s), -127.f), 127.f);
    float d = fminf(fmaxf(rintf(v.w / s), -127.f), 127.f);
    ((ushort4*)xq)[i] = make_ushort4(f2bf(a), f2bf(b), f2bf(c), f2bf(d));
  }
}

// ---------------- 3) GEMM split-K8: BM=256,BN=256,BK=64; 8 waves 2x4, wave 128x64 ----------------
// R12 sync envelope, refined into 4 sub-phases per K-tile (fm-half x K-half):
// each sub-phase issues 2 staging loads (A,A,B,B across phases), reads af[4]+bf[4],
// runs one setprio'd 16-MFMA cluster. Gate = vmcnt(2) at sub-phase 1 (prior tile's
// 8 loads drained; this iter's first 2 stay in flight). Stages target buf nxt whose
// readers finished at the previous trailing barrier (same proof as R12).
__global__ __launch_bounds__(512) void k_gemm(const unsigned short* __restrict__ Xq,
                                              const unsigned short* __restrict__ W,
                                              unsigned short* __restrict__ P) {
  __shared__ unsigned short Al[2][256 * 64];  // 2 x 32KB, 128B rows, XOR swz
  __shared__ unsigned short Bl[2][256 * 64];  // 2 x 32KB
  const int t = threadIdx.x, lane = t & 63, wid = t >> 6;  // wid 0..7
  const int wg = (blockIdx.x & 7) * 32 + (blockIdx.x >> 3);  // bijective, 256%8==0
  const int sk = wg >> 5;        // 0..7 == XCD id -> W K-panel 4MB = its L2
  const int bm = (wg >> 4) & 1;  // 0..1
  const int bn = wg & 15;        // 0..15
  const int wm = wid >> 2, wn = wid & 3;  // wave tile 128x64 (2x4 waves)
  const int kbase = sk * 512;
  f32x4 acc[8][4];
#pragma unroll
  for (int a = 0; a < 8; ++a)
#pragma unroll
    for (int b = 0; b < 4; ++b) acc[a][b] = (f32x4)(0.f);

  const int lr = lane >> 3;         // row-in-chunk 0..7
  const int lcb = (lane & 7) * 16;  // byte col in 128B row

  // one half-stage = 2 chunks (this wave's pair c2 in 0..1) of A or B
  auto STAGE_A2 = [&](int buf, int kt, int half) {
    const int k0 = kbase + kt * 64;
#pragma unroll
    for (int c = 0; c < 2; ++c) {
      int chunk = wid * 4 + half * 2 + c;
      int r = chunk * 8 + lr;
      int colb = lcb ^ ((r & 7) << 4);
      load_lds16(Xq + ((size_t)(bm * 256 + r) << 12) + k0 + (colb >> 1), &Al[buf][chunk * 512]);
    }
  };
  auto STAGE_B2 = [&](int buf, int kt, int half) {
    const int k0 = kbase + kt * 64;
#pragma unroll
    for (int c = 0; c < 2; ++c) {
      int chunk = wid * 4 + half * 2 + c;
      int r = chunk * 8 + lr;
      int colb = lcb ^ ((r & 7) << 4);
      load_lds16(W + ((size_t)(bn * 256 + r) << 12) + k0 + (colb >> 1), &Bl[buf][chunk * 512]);
    }
  };

  // prologue: full tile 0 into buf0 -> 8 loads/wave outstanding
  STAGE_A2(0, 0, 0); STAGE_A2(0, 0, 1);
  STAGE_B2(0, 0, 0); STAGE_B2(0, 0, 1);

  for (int it = 0; it < 8; ++it) {
    const int cur = it & 1, nxt = cur ^ 1;
    const int ktn = (it + 1) & 7;  // it=7 restages kt=0 (dummy, never read)
#pragma unroll
    for (int sp = 0; sp < 4; ++sp) {
      // issue this sub-phase's 2 staging loads (A halves then B halves)
      if (sp == 0)      STAGE_A2(nxt, ktn, 0);
      else if (sp == 1) STAGE_A2(nxt, ktn, 1);
      else if (sp == 2) STAGE_B2(nxt, ktn, 0);
      else              STAGE_B2(nxt, ktn, 1);
      if (sp == 0) {
        __builtin_amdgcn_sched_barrier(0);
        asm volatile("s_waitcnt vmcnt(2)" ::: "memory");  // tile it landed; 2 in flight
        __builtin_amdgcn_sched_barrier(0);
        __builtin_amdgcn_s_barrier();                     // buf[cur] ready for all waves
        __builtin_amdgcn_sched_barrier(0);
      }
      const int fmh = sp & 1;        // fm half: fragments fmh*4..+4
      const int ksh = sp >> 1;       // K half: cols ksh*64..+64 bytes
      bf16x8 af[4], bfr[4];
#pragma unroll
      for (int f = 0; f < 4; ++f) {
        int fm = fmh * 4 + f;
        int r = wm * 128 + fm * 16 + (lane & 15);
        int colb = (ksh * 64 + ((lane >> 4) * 16)) ^ ((r & 7) << 4);
        af[f] = *(const bf16x8*)((const char*)&Al[cur][0] + r * 128 + colb);
      }
#pragma unroll
      for (int fn = 0; fn < 4; ++fn) {
        int r = wn * 64 + fn * 16 + (lane & 15);
        int colb = (ksh * 64 + ((lane >> 4) * 16)) ^ ((r & 7) << 4);
        bfr[fn] = *(const bf16x8*)((const char*)&Bl[cur][0] + r * 128 + colb);
      }
      __builtin_amdgcn_sched_barrier(0);
      __builtin_amdgcn_s_setprio(1);
#pragma unroll
      for (int f = 0; f < 4; ++f)
#pragma unroll
        for (int fn = 0; fn < 4; ++fn)
          acc[fmh * 4 + f][fn] =
              __builtin_amdgcn_mfma_f32_16x16x32_bf16(af[f], bfr[fn], acc[fmh * 4 + f][fn], 0, 0, 0);
      __builtin_amdgcn_s_setprio(0);
      __builtin_amdgcn_sched_barrier(0);
    }
    __builtin_amdgcn_s_barrier();  // reads of cur done before next iter's stages land
  }

  // register-native coalesced bf16 partial store (512B contiguous per inst)
  unsigned short* Pk = P + (size_t)sk * 2097152;
  const int blkL = bm * 16 + bn;  // 0..31
#pragma unroll
  for (int fm = 0; fm < 8; ++fm) {
#pragma unroll
    for (int fn = 0; fn < 4; ++fn) {
      int idx = (((blkL * 8 + wid) * 32 + fm * 4 + fn) * 64) + lane;
      ushort4 o = make_ushort4(f2bf(acc[fm][fn][0]), f2bf(acc[fm][fn][1]),
                               f2bf(acc[fm][fn][2]), f2bf(acc[fm][fn][3]));
      ((ushort4*)Pk)[idx] = o;
    }
  }
}

// ---------------- 4) epilogue: out = (sum of 8 native-layout partials) * s + bias ----------------
__global__ __launch_bounds__(256) void k_epi(float* __restrict__ out,
                                             const unsigned short* __restrict__ P,
                                             const float* __restrict__ scl,
                                             const float* __restrict__ bias) {
  int g = blockIdx.x * 256 + threadIdx.x;  // 524288 threads, 4 elems each
  const int lane = g & 63;
  const int ff = (g >> 6) & 31;
  const int fn = ff & 3, fm = ff >> 2;
  const int wid = (g >> 11) & 7;
  const int blkL = g >> 14;  // 0..31
  const int bm = blkL >> 4, bn = blkL & 15;
  const int wm = wid >> 2, wn = wid & 3;
  const int row0 = bm * 256 + wm * 128 + fm * 16 + ((lane >> 4) << 2);
  const int col = bn * 256 + wn * 64 + fn * 16 + (lane & 15);
  const float s = scl[0];
  const float bv = bias[col];
  float sum[4] = {0.f, 0.f, 0.f, 0.f};
#pragma unroll
  for (int k = 0; k < 8; ++k) {
    ushort4 p = ((const ushort4*)(P + (size_t)k * 2097152))[g];
    sum[0] += bf2f(p.x); sum[1] += bf2f(p.y); sum[2] += bf2f(p.z); sum[3] += bf2f(p.w);
  }
#pragma unroll
  for (int i = 0; i < 4; ++i) out[(size_t)(row0 + i) * 4096 + col] = sum[i] * s + bv;
}

// ---------------- fallback GEMM (used if ws too small for partials) ----------------
__global__ __launch_bounds__(512) void k_gemm_fb(const unsigned short* __restrict__ Xq,
                                                 const unsigned short* __restrict__ W,
                                                 const float* __restrict__ scl,
                                                 const float* __restrict__ bias,
                                                 float* __restrict__ out) {
  __shared__ unsigned short Al[4][128 * 64];
  __shared__ unsigned short Bl[4][64 * 64];
  const int t = threadIdx.x, lane = t & 63, wid = t >> 6;
  const int wg = (blockIdx.x & 7) * 32 + (blockIdx.x >> 3);
  const int bm = wg & 3;
  const int bn = wg >> 2;
  const int wm = wid >> 1, wn = wid & 1;
  f32x4 acc[2][2];
#pragma unroll
  for (int a = 0; a < 2; ++a)
#pragma unroll
    for (int b = 0; b < 2; ++b) acc[a][b] = (f32x4)(0.f);
  const int lr = lane >> 3;
  const int lcb = (lane & 7) * 16;
  auto STAGE = [&](int buf, int kt) {
    const int k0 = kt * 64;
#pragma unroll
    for (int c = 0; c < 2; ++c) {
      int chunk = wid * 2 + c;
      int r = chunk * 8 + lr;
      int colb = lcb ^ ((r & 7) << 4);
      load_lds16(Xq + ((size_t)(bm * 128 + r) << 12) + k0 + (colb >> 1), &Al[buf][chunk * 512]);
    }
    {
      int r = wid * 8 + lr;
      int colb = lcb ^ ((r & 7) << 4);
      load_lds16(W + ((size_t)(bn * 64 + r) << 12) + k0 + (colb >> 1), &Bl[buf][wid * 512]);
    }
  };
  auto COMPUTE = [&](int buf) {
#pragma unroll
    for (int ks = 0; ks < 2; ++ks) {
      bf16x8 af[2], bfr[2];
#pragma unroll
      for (int fm = 0; fm < 2; ++fm) {
        int r = wm * 32 + fm * 16 + (lane & 15);
        int colb = (ks * 64 + ((lane >> 4) * 16)) ^ ((r & 7) << 4);
        af[fm] = *(const bf16x8*)((const char*)&Al[buf][0] + r * 128 + colb);
      }
#pragma unroll
      for (int fn = 0; fn < 2; ++fn) {
        int r = wn * 32 + fn * 16 + (lane & 15);
        int colb = (ks * 64 + ((lane >> 4) * 16)) ^ ((r & 7) << 4);
        bfr[fn] = *(const bf16x8*)((const char*)&Bl[buf][0] + r * 128 + colb);
      }
#pragma unroll
      for (int fm = 0; fm < 2; ++fm)
#pragma unroll
        for (int fn = 0; fn < 2; ++fn)
          acc[fm][fn] = __builtin_amdgcn_mfma_f32_16x16x32_bf16(af[fm], bfr[fn], acc[fm][fn], 0, 0, 0);
    }
  };
  STAGE(0, 0); STAGE(1, 1); STAGE(2, 2);
  for (int t64 = 0; t64 < 64; ++t64) {
    STAGE((t64 + 3) & 3, (t64 + 3) & 63);
    __builtin_amdgcn_sched_barrier(0);
    asm volatile("s_waitcnt vmcnt(9)" ::: "memory");
    __builtin_amdgcn_sched_barrier(0);
    __builtin_amdgcn_s_barrier();
    __builtin_amdgcn_sched_barrier(0);
    COMPUTE(t64 & 3);
    __builtin_amdgcn_sched_barrier(0);
    __builtin_amdgcn_s_barrier();
  }
  const float s = scl[0];
#pragma unroll
  for (int fn = 0; fn < 2; ++fn) {
    int col = bn * 64 + wn * 32 + fn * 16 + (lane & 15);
    float bv = bias[col];
#pragma unroll
    for (int fm = 0; fm < 2; ++fm) {
#pragma unroll
      for (int i = 0; i < 4; ++i) {
        int row = bm * 128 + wm * 32 + fm * 16 + (lane >> 4) * 4 + i;
        out[(size_t)row * 4096 + col] = acc[fm][fn][i] * s + bv;
      }
    }
  }
}

extern "C" void kernel_launch(void* const* d_in, const int* in_sizes, int n_in,
                              void* d_out, int out_size, void* d_ws, size_t ws_size,
                              hipStream_t stream) {
  const float* x    = (const float*)d_in[0];  // (1,512,4096)
  const float* Ysg  = (const float*)d_in[1];  // (2,32,32,128,16)
  const float* Zsg  = (const float*)d_in[2];  // (2,32,32,16,128)
  const float* Ysc  = (const float*)d_in[3];  // (2,32,32)
  const float* Zsc  = (const float*)d_in[4];  // (2,32,32)
  const float* A    = (const float*)d_in[5];  // (2,32,32,4)
  const float* bias = (const float*)d_in[6];  // (4096,)
  float* out = (float*)d_out;

  char* ws = (char*)d_ws;
  float* scl  = (float*)ws;                  // [0] act_scale
  float* part = (float*)(ws + 256);          // 512 f32 partials
  unsigned short* Xq = (unsigned short*)(ws + 65536);                    // 4MB bf16
  unsigned short* W  = (unsigned short*)(ws + 65536 + (size_t)4194304);  // 32MB bf16
  unsigned short* P  = (unsigned short*)(ws + 65536 + (size_t)4194304 + (size_t)33554432);  // 32MB bf16 partials (8 slices)

  k_minmax_part<<<dim3(256), dim3(256), 0, stream>>>(x, part);
  k_fused<<<dim3(3072), dim3(256), 0, stream>>>(x, part, Ysg, Zsg, Ysc, Zsc, A, scl, Xq, W);
  if (ws_size >= (size_t)65536 + 4194304 + 33554432 + 33554432) {
    k_gemm<<<dim3(256), dim3(512), 0, stream>>>(Xq, W, P);
    k_epi<<<dim3(2048), dim3(256), 0, stream>>>(out, P, scl, bias);
  } else {
    k_gemm_fb<<<dim3(256), dim3(512), 0, stream>>>(Xq, W, scl, bias, out);
  }
}

// Round 15
// 56.408 us; speedup vs baseline: 1.0605x; 1.0276x over previous
//
#include <hip/hip_runtime.h>
#include <hip/hip_bf16.h>

// BQQ dims: P=2, J=32, K=32, M=128, L=16, N=128; B=512; in=kn=4096; out=jm=4096
typedef __attribute__((ext_vector_type(4))) float f32x4;
typedef __attribute__((ext_vector_type(8))) short bf16x8;
typedef __attribute__((ext_vector_type(4))) unsigned int u32x4;

#define GLOBAL_AS __attribute__((address_space(1)))
#define LDS_AS __attribute__((address_space(3)))

static __device__ __forceinline__ unsigned short f2bf(float f) {
  __hip_bfloat16 h = __float2bfloat16(f);
  return __builtin_bit_cast(unsigned short, h);
}
static __device__ __forceinline__ float bf2f(unsigned short u) {
  unsigned int v = ((unsigned int)u) << 16;
  return __builtin_bit_cast(float, v);
}
static __device__ __forceinline__ void load_lds16(const void* g, void* l) {
  __builtin_amdgcn_global_load_lds((GLOBAL_AS void*)g, (LDS_AS void*)l, 16, 0, 0);
}

// ---------------- 1) per-block min/max of input (2M f32), 256 blocks ----------------
__global__ __launch_bounds__(256) void k_minmax_part(const float* __restrict__ x,
                                                     float* __restrict__ part) {
  int tid = blockIdx.x * 256 + threadIdx.x;
  const float4* xv = (const float4*)x;
  float mn = 3.4e38f, mx = -3.4e38f;
#pragma unroll
  for (int rep = 0; rep < 8; ++rep) {
    float4 v = xv[tid + rep * 65536];
    mn = fminf(mn, fminf(fminf(v.x, v.y), fminf(v.z, v.w)));
    mx = fmaxf(mx, fmaxf(fmaxf(v.x, v.y), fmaxf(v.z, v.w)));
  }
#pragma unroll
  for (int o = 32; o > 0; o >>= 1) {
    mn = fminf(mn, __shfl_down(mn, o));
    mx = fmaxf(mx, __shfl_down(mx, o));
  }
  __shared__ float smn[4], smx[4];
  int lane = threadIdx.x & 63, w = threadIdx.x >> 6;
  if (lane == 0) { smn[w] = mn; smx[w] = mx; }
  __syncthreads();
  if (threadIdx.x == 0) {
    mn = fminf(fminf(smn[0], smn[1]), fminf(smn[2], smn[3]));
    mx = fmaxf(fmaxf(smx[0], smx[1]), fmaxf(smx[2], smx[3]));
    part[2 * blockIdx.x] = mn;
    part[2 * blockIdx.x + 1] = mx;
  }
}

// ---------------- 2) fused: blocks 0..1023 = build W (MFMA); 1024..3071 = quantize ----------------
__global__ __launch_bounds__(256) void k_fused(const float* __restrict__ x,
                                               const float* __restrict__ part,
                                               const float* __restrict__ Ysg,
                                               const float* __restrict__ Zsg,
                                               const float* __restrict__ Ysc,
                                               const float* __restrict__ Zsc,
                                               const float* __restrict__ Acoef,
                                               float* __restrict__ scl,
                                               unsigned short* __restrict__ xq,
                                               unsigned short* __restrict__ W) {
  const int t = threadIdx.x;
  if (blockIdx.x < 1024) {
    // ---- build_w (MFMA) ----
    const int jk = blockIdx.x;  // j*32+k
    __shared__ unsigned short Yb[2 * 128 * 24];  // [p*128+m][24] halves; data in [0..16)
    __shared__ unsigned short Zb[128 * 36];      // [n][36] halves; data pl in [0..32)
    __shared__ float B1p[2][128];
    __shared__ float C1[128];
    float cf0[2], cf2[2], cf4[2];
    float Dv;
    {
      float ys0 = Ysc[jk], zs0 = Zsc[jk], ys1 = Ysc[1024 + jk], zs1 = Zsc[1024 + jk];
      const float* A0p = Acoef + (size_t)jk * 4;
      const float* A1p = Acoef + (size_t)(1024 + jk) * 4;
      cf0[0] = A0p[0] * ys0 * zs0; cf0[1] = A1p[0] * ys1 * zs1;
      cf2[0] = A0p[1] * ys0;       cf2[1] = A1p[1] * ys1;
      cf4[0] = A0p[2] * zs0;       cf4[1] = A1p[2] * zs1;
      Dv = A0p[3] + A1p[3];
    }
#pragma unroll
    for (int rep = 0; rep < 4; ++rep) {
      int q = rep * 256 + t;
      int l0 = (q & 3) * 4, m = (q >> 2) & 127, p = q >> 9;
      float4 v = *(const float4*)(Ysg + (size_t)(p * 1024 + jk) * 2048 + m * 16 + l0);
      float s4 = v.x + v.y + v.z + v.w;
      s4 += __shfl_xor(s4, 1);
      s4 += __shfl_xor(s4, 2);
      if ((t & 3) == 0) B1p[p][m] = s4;
      float c0 = cf0[p];
      ushort4 o = make_ushort4(f2bf(c0 * v.x), f2bf(c0 * v.y), f2bf(c0 * v.z), f2bf(c0 * v.w));
      *(ushort4*)&Yb[(p * 128 + m) * 24 + l0] = o;
    }
#pragma unroll
    for (int rep = 0; rep < 4; ++rep) {
      int q = rep * 256 + t;
      int n0 = (q & 31) * 4, l = (q >> 5) & 15, p = q >> 9;
      float4 v = *(const float4*)(Zsg + (size_t)(p * 1024 + jk) * 2048 + l * 128 + n0);
      int pl = p * 16 + l;
      Zb[(n0 + 0) * 36 + pl] = f2bf(v.x);
      Zb[(n0 + 1) * 36 + pl] = f2bf(v.y);
      Zb[(n0 + 2) * 36 + pl] = f2bf(v.z);
      Zb[(n0 + 3) * 36 + pl] = f2bf(v.w);
    }
    __syncthreads();
    if (t < 128) {
      float s0 = 0.f, s1 = 0.f;
#pragma unroll
      for (int l = 0; l < 16; ++l) {
        s0 += bf2f(Zb[t * 36 + l]);
        s1 += bf2f(Zb[t * 36 + 16 + l]);
      }
      C1[t] = cf4[0] * s0 + cf4[1] * s1;
    }
    __syncthreads();
    const int lane = t & 63, wid = t >> 6;
    const int wm = wid >> 1, wn = wid & 1;
    const int grp = lane >> 4;
    bf16x8 af[4], bfr[4];
#pragma unroll
    for (int fm = 0; fm < 4; ++fm) {
      int m = wm * 64 + fm * 16 + (lane & 15);
      af[fm] = *(const bf16x8*)((const char*)Yb + ((grp >> 1) * 128 + m) * 48 + (grp & 1) * 16);
    }
#pragma unroll
    for (int fn = 0; fn < 4; ++fn) {
      int n = wn * 64 + fn * 16 + (lane & 15);
      const char* zp = (const char*)Zb + n * 72 + grp * 16;
      uint2 z0 = *(const uint2*)zp;
      uint2 z1 = *(const uint2*)(zp + 8);
      u32x4 zw; zw[0] = z0.x; zw[1] = z0.y; zw[2] = z1.x; zw[3] = z1.y;
      bfr[fn] = __builtin_bit_cast(bf16x8, zw);
    }
    f32x4 acc[4][4];
#pragma unroll
    for (int fm = 0; fm < 4; ++fm)
#pragma unroll
      for (int fn = 0; fn < 4; ++fn)
        acc[fm][fn] = __builtin_amdgcn_mfma_f32_16x16x32_bf16(af[fm], bfr[fn], (f32x4)(0.f), 0, 0, 0);
    const int j = jk >> 5, k = jk & 31;
    float c1v[4];
#pragma unroll
    for (int fn = 0; fn < 4; ++fn) c1v[fn] = C1[wn * 64 + fn * 16 + (lane & 15)];
#pragma unroll
    for (int fm = 0; fm < 4; ++fm) {
#pragma unroll
      for (int i = 0; i < 4; ++i) {
        int row = wm * 64 + fm * 16 + (grp)*4 + i;
        float b1v = cf2[0] * B1p[0][row] + cf2[1] * B1p[1][row] + Dv;
        size_t rowoff = (size_t)(j * 128 + row) * 4096 + (size_t)(k * 128);
#pragma unroll
        for (int fn = 0; fn < 4; ++fn) {
          int col = wn * 64 + fn * 16 + (lane & 15);
          W[rowoff + col] = f2bf(acc[fm][fn][i] + b1v + c1v[fn]);
        }
      }
    }
  } else {
    // ---- quantize ----
    const int qb = blockIdx.x - 1024;
    float2 v2 = ((const float2*)part)[t];
    float mn = v2.x, mx = v2.y;
#pragma unroll
    for (int o = 32; o > 0; o >>= 1) {
      mn = fminf(mn, __shfl_down(mn, o));
      mx = fmaxf(mx, __shfl_down(mx, o));
    }
    __shared__ float smn2[4], smx2[4], ssc[1];
    int lane = t & 63, w = t >> 6;
    if (lane == 0) { smn2[w] = mn; smx2[w] = mx; }
    __syncthreads();
    if (t == 0) {
      mn = fminf(fminf(smn2[0], smn2[1]), fminf(smn2[2], smn2[3]));
      mx = fmaxf(fmaxf(smx2[0], smx2[1]), fmaxf(smx2[2], smx2[3]));
      ssc[0] = fmaxf((mx - mn) / 254.0f, 1e-8f);
      if (qb == 0) scl[0] = ssc[0];
    }
    __syncthreads();
    const float s = ssc[0];
    int i = qb * 256 + t;
    float4 v = ((const float4*)x)[i];
    float a = fminf(fmaxf(rintf(v.x / s), -127.f), 127.f);
    float b = fminf(fmaxf(rintf(v.y / s), -127.f), 127.f);
    float c = fminf(fmaxf(rintf(v.z / s), -127.f), 127.f);
    float d = fminf(fmaxf(rintf(v.w / s), -127.f), 127.f);
    ((ushort4*)xq)[i] = make_ushort4(f2bf(a), f2bf(b), f2bf(c), f2bf(d));
  }
}

// ---------------- 3) GEMM split-K8: BM=256,BN=256,BK=64; 8 waves 2x4, wave 128x64 ----------------
// R12 hazard envelope + m201-style per-phase BARRIERS (4 phases/K-tile):
//   ph0: stage A-half0(nxt); vmcnt(2); s_barrier; ds_read bfr(ks0)+af(q00);
//        lgkmcnt(0); setprio MFMA x16
//   ph1: ds_read af(q10) [cur stable, latency hides under barrier]; stage A-half1;
//        s_barrier; lgkmcnt(0); setprio MFMA x16
//   ph2: ds_read bfr(ks1)+af(q01); stage B-half0; s_barrier; lgkm; MFMA x16
//   ph3: ds_read af(q11); stage B-half1; s_barrier; lgkm; MFMA x16
//   trailing s_barrier (reads of cur done before next iter's stages target cur^1..)
// Barriers make waves ping-pong ds_read<->MFMA in anti-phase (m201 mechanism);
// counted vmcnt once per tile keeps 8 loads in flight across all barriers.
__global__ __launch_bounds__(512) void k_gemm(const unsigned short* __restrict__ Xq,
                                              const unsigned short* __restrict__ W,
                                              unsigned short* __restrict__ P) {
  __shared__ unsigned short Al[2][256 * 64];  // 2 x 32KB, 128B rows, XOR swz
  __shared__ unsigned short Bl[2][256 * 64];  // 2 x 32KB
  const int t = threadIdx.x, lane = t & 63, wid = t >> 6;  // wid 0..7
  const int wg = (blockIdx.x & 7) * 32 + (blockIdx.x >> 3);  // bijective, 256%8==0
  const int sk = wg >> 5;        // 0..7 == XCD id -> W K-panel 4MB = its L2
  const int bm = (wg >> 4) & 1;  // 0..1
  const int bn = wg & 15;        // 0..15
  const int wm = wid >> 2, wn = wid & 3;  // wave tile 128x64 (2x4 waves)
  const int kbase = sk * 512;
  f32x4 acc[8][4];
#pragma unroll
  for (int a = 0; a < 8; ++a)
#pragma unroll
    for (int b = 0; b < 4; ++b) acc[a][b] = (f32x4)(0.f);

  const int lr = lane >> 3;         // row-in-chunk 0..7
  const int lcb = (lane & 7) * 16;  // byte col in 128B row

  auto STAGE_A2 = [&](int buf, int kt, int half) {
    const int k0 = kbase + kt * 64;
#pragma unroll
    for (int c = 0; c < 2; ++c) {
      int chunk = wid * 4 + half * 2 + c;
      int r = chunk * 8 + lr;
      int colb = lcb ^ ((r & 7) << 4);
      load_lds16(Xq + ((size_t)(bm * 256 + r) << 12) + k0 + (colb >> 1), &Al[buf][chunk * 512]);
    }
  };
  auto STAGE_B2 = [&](int buf, int kt, int half) {
    const int k0 = kbase + kt * 64;
#pragma unroll
    for (int c = 0; c < 2; ++c) {
      int chunk = wid * 4 + half * 2 + c;
      int r = chunk * 8 + lr;
      int colb = lcb ^ ((r & 7) << 4);
      load_lds16(W + ((size_t)(bn * 256 + r) << 12) + k0 + (colb >> 1), &Bl[buf][chunk * 512]);
    }
  };
  auto READ_AF = [&](int cur, int fmh, int ksh, bf16x8* af) {
#pragma unroll
    for (int f = 0; f < 4; ++f) {
      int fm = fmh * 4 + f;
      int r = wm * 128 + fm * 16 + (lane & 15);
      int colb = (ksh * 64 + ((lane >> 4) * 16)) ^ ((r & 7) << 4);
      af[f] = *(const bf16x8*)((const char*)&Al[cur][0] + r * 128 + colb);
    }
  };
  auto READ_BF = [&](int cur, int ksh, bf16x8* bfr) {
#pragma unroll
    for (int fn = 0; fn < 4; ++fn) {
      int r = wn * 64 + fn * 16 + (lane & 15);
      int colb = (ksh * 64 + ((lane >> 4) * 16)) ^ ((r & 7) << 4);
      bfr[fn] = *(const bf16x8*)((const char*)&Bl[cur][0] + r * 128 + colb);
    }
  };
  auto MFMA16 = [&](int fmh, const bf16x8* af, const bf16x8* bfr) {
    __builtin_amdgcn_s_setprio(1);
#pragma unroll
    for (int f = 0; f < 4; ++f)
#pragma unroll
      for (int fn = 0; fn < 4; ++fn)
        acc[fmh * 4 + f][fn] =
            __builtin_amdgcn_mfma_f32_16x16x32_bf16(af[f], bfr[fn], acc[fmh * 4 + f][fn], 0, 0, 0);
    __builtin_amdgcn_s_setprio(0);
  };

  // prologue: full tile 0 into buf0 -> 8 loads/wave outstanding
  STAGE_A2(0, 0, 0); STAGE_A2(0, 0, 1);
  STAGE_B2(0, 0, 0); STAGE_B2(0, 0, 1);

  for (int it = 0; it < 8; ++it) {
    const int cur = it & 1, nxt = cur ^ 1;
    const int ktn = (it + 1) & 7;  // it=7 restages kt=0 (dummy, never read)
    bf16x8 af[4], bfr[4];
    // ---- phase 0: quad (fmh=0, ks=0) ----
    STAGE_A2(nxt, ktn, 0);
    __builtin_amdgcn_sched_barrier(0);
    asm volatile("s_waitcnt vmcnt(2)" ::: "memory");  // tile it landed; 2 in flight
    __builtin_amdgcn_sched_barrier(0);
    __builtin_amdgcn_s_barrier();                     // buf[cur] ready for all waves
    __builtin_amdgcn_sched_barrier(0);
    READ_BF(cur, 0, bfr);
    READ_AF(cur, 0, 0, af);
    asm volatile("s_waitcnt lgkmcnt(0)" ::: "memory");
    __builtin_amdgcn_sched_barrier(0);
    MFMA16(0, af, bfr);
    // ---- phase 1: quad (1, 0) ----
    READ_AF(cur, 1, 0, af);     // issued pre-barrier; latency hides under barrier wait
    STAGE_A2(nxt, ktn, 1);
    __builtin_amdgcn_s_barrier();
    asm volatile("s_waitcnt lgkmcnt(0)" ::: "memory");
    __builtin_amdgcn_sched_barrier(0);
    MFMA16(1, af, bfr);
    // ---- phase 2: quad (0, 1) ----
    READ_BF(cur, 1, bfr);
    READ_AF(cur, 0, 1, af);
    STAGE_B2(nxt, ktn, 0);
    __builtin_amdgcn_s_barrier();
    asm volatile("s_waitcnt lgkmcnt(0)" ::: "memory");
    __builtin_amdgcn_sched_barrier(0);
    MFMA16(0, af, bfr);
    // ---- phase 3: quad (1, 1) ----
    READ_AF(cur, 1, 1, af);
    STAGE_B2(nxt, ktn, 1);
    __builtin_amdgcn_s_barrier();
    asm volatile("s_waitcnt lgkmcnt(0)" ::: "memory");
    __builtin_amdgcn_sched_barrier(0);
    MFMA16(1, af, bfr);
    __builtin_amdgcn_s_barrier();  // reads of cur done before next iter's stages land
  }

  // register-native coalesced bf16 partial store (512B contiguous per inst)
  unsigned short* Pk = P + (size_t)sk * 2097152;
  const int blkL = bm * 16 + bn;  // 0..31
#pragma unroll
  for (int fm = 0; fm < 8; ++fm) {
#pragma unroll
    for (int fn = 0; fn < 4; ++fn) {
      int idx = (((blkL * 8 + wid) * 32 + fm * 4 + fn) * 64) + lane;
      ushort4 o = make_ushort4(f2bf(acc[fm][fn][0]), f2bf(acc[fm][fn][1]),
                               f2bf(acc[fm][fn][2]), f2bf(acc[fm][fn][3]));
      ((ushort4*)Pk)[idx] = o;
    }
  }
}

// ---------------- 4) epilogue: out = (sum of 8 native-layout partials) * s + bias ----------------
__global__ __launch_bounds__(256) void k_epi(float* __restrict__ out,
                                             const unsigned short* __restrict__ P,
                                             const float* __restrict__ scl,
                                             const float* __restrict__ bias) {
  int g = blockIdx.x * 256 + threadIdx.x;  // 524288 threads, 4 elems each
  const int lane = g & 63;
  const int ff = (g >> 6) & 31;
  const int fn = ff & 3, fm = ff >> 2;
  const int wid = (g >> 11) & 7;
  const int blkL = g >> 14;  // 0..31
  const int bm = blkL >> 4, bn = blkL & 15;
  const int wm = wid >> 2, wn = wid & 3;
  const int row0 = bm * 256 + wm * 128 + fm * 16 + ((lane >> 4) << 2);
  const int col = bn * 256 + wn * 64 + fn * 16 + (lane & 15);
  const float s = scl[0];
  const float bv = bias[col];
  float sum[4] = {0.f, 0.f, 0.f, 0.f};
#pragma unroll
  for (int k = 0; k < 8; ++k) {
    ushort4 p = ((const ushort4*)(P + (size_t)k * 2097152))[g];
    sum[0] += bf2f(p.x); sum[1] += bf2f(p.y); sum[2] += bf2f(p.z); sum[3] += bf2f(p.w);
  }
#pragma unroll
  for (int i = 0; i < 4; ++i) out[(size_t)(row0 + i) * 4096 + col] = sum[i] * s + bv;
}

// ---------------- fallback GEMM (used if ws too small for partials) ----------------
__global__ __launch_bounds__(512) void k_gemm_fb(const unsigned short* __restrict__ Xq,
                                                 const unsigned short* __restrict__ W,
                                                 const float* __restrict__ scl,
                                                 const float* __restrict__ bias,
                                                 float* __restrict__ out) {
  __shared__ unsigned short Al[4][128 * 64];
  __shared__ unsigned short Bl[4][64 * 64];
  const int t = threadIdx.x, lane = t & 63, wid = t >> 6;
  const int wg = (blockIdx.x & 7) * 32 + (blockIdx.x >> 3);
  const int bm = wg & 3;
  const int bn = wg >> 2;
  const int wm = wid >> 1, wn = wid & 1;
  f32x4 acc[2][2];
#pragma unroll
  for (int a = 0; a < 2; ++a)
#pragma unroll
    for (int b = 0; b < 2; ++b) acc[a][b] = (f32x4)(0.f);
  const int lr = lane >> 3;
  const int lcb = (lane & 7) * 16;
  auto STAGE = [&](int buf, int kt) {
    const int k0 = kt * 64;
#pragma unroll
    for (int c = 0; c < 2; ++c) {
      int chunk = wid * 2 + c;
      int r = chunk * 8 + lr;
      int colb = lcb ^ ((r & 7) << 4);
      load_lds16(Xq + ((size_t)(bm * 128 + r) << 12) + k0 + (colb >> 1), &Al[buf][chunk * 512]);
    }
    {
      int r = wid * 8 + lr;
      int colb = lcb ^ ((r & 7) << 4);
      load_lds16(W + ((size_t)(bn * 64 + r) << 12) + k0 + (colb >> 1), &Bl[buf][wid * 512]);
    }
  };
  auto COMPUTE = [&](int buf) {
#pragma unroll
    for (int ks = 0; ks < 2; ++ks) {
      bf16x8 af[2], bfr[2];
#pragma unroll
      for (int fm = 0; fm < 2; ++fm) {
        int r = wm * 32 + fm * 16 + (lane & 15);
        int colb = (ks * 64 + ((lane >> 4) * 16)) ^ ((r & 7) << 4);
        af[fm] = *(const bf16x8*)((const char*)&Al[buf][0] + r * 128 + colb);
      }
#pragma unroll
      for (int fn = 0; fn < 2; ++fn) {
        int r = wn * 32 + fn * 16 + (lane & 15);
        int colb = (ks * 64 + ((lane >> 4) * 16)) ^ ((r & 7) << 4);
        bfr[fn] = *(const bf16x8*)((const char*)&Bl[buf][0] + r * 128 + colb);
      }
#pragma unroll
      for (int fm = 0; fm < 2; ++fm)
#pragma unroll
        for (int fn = 0; fn < 2; ++fn)
          acc[fm][fn] = __builtin_amdgcn_mfma_f32_16x16x32_bf16(af[fm], bfr[fn], acc[fm][fn], 0, 0, 0);
    }
  };
  STAGE(0, 0); STAGE(1, 1); STAGE(2, 2);
  for (int t64 = 0; t64 < 64; ++t64) {
    STAGE((t64 + 3) & 3, (t64 + 3) & 63);
    __builtin_amdgcn_sched_barrier(0);
    asm volatile("s_waitcnt vmcnt(9)" ::: "memory");
    __builtin_amdgcn_sched_barrier(0);
    __builtin_amdgcn_s_barrier();
    __builtin_amdgcn_sched_barrier(0);
    COMPUTE(t64 & 3);
    __builtin_amdgcn_sched_barrier(0);
    __builtin_amdgcn_s_barrier();
  }
  const float s = scl[0];
#pragma unroll
  for (int fn = 0; fn < 2; ++fn) {
    int col = bn * 64 + wn * 32 + fn * 16 + (lane & 15);
    float bv = bias[col];
#pragma unroll
    for (int fm = 0; fm < 2; ++fm) {
#pragma unroll
      for (int i = 0; i < 4; ++i) {
        int row = bm * 128 + wm * 32 + fm * 16 + (lane >> 4) * 4 + i;
        out[(size_t)row * 4096 + col] = acc[fm][fn][i] * s + bv;
      }
    }
  }
}

extern "C" void kernel_launch(void* const* d_in, const int* in_sizes, int n_in,
                              void* d_out, int out_size, void* d_ws, size_t ws_size,
                              hipStream_t stream) {
  const float* x    = (const float*)d_in[0];  // (1,512,4096)
  const float* Ysg  = (const float*)d_in[1];  // (2,32,32,128,16)
  const float* Zsg  = (const float*)d_in[2];  // (2,32,32,16,128)
  const float* Ysc  = (const float*)d_in[3];  // (2,32,32)
  const float* Zsc  = (const float*)d_in[4];  // (2,32,32)
  const float* A    = (const float*)d_in[5];  // (2,32,32,4)
  const float* bias = (const float*)d_in[6];  // (4096,)
  float* out = (float*)d_out;

  char* ws = (char*)d_ws;
  float* scl  = (float*)ws;                  // [0] act_scale
  float* part = (float*)(ws + 256);          // 512 f32 partials
  unsigned short* Xq = (unsigned short*)(ws + 65536);                    // 4MB bf16
  unsigned short* W  = (unsigned short*)(ws + 65536 + (size_t)4194304);  // 32MB bf16
  unsigned short* P  = (unsigned short*)(ws + 65536 + (size_t)4194304 + (size_t)33554432);  // 32MB bf16 partials (8 slices)

  k_minmax_part<<<dim3(256), dim3(256), 0, stream>>>(x, part);
  k_fused<<<dim3(3072), dim3(256), 0, stream>>>(x, part, Ysg, Zsg, Ysc, Zsc, A, scl, Xq, W);
  if (ws_size >= (size_t)65536 + 4194304 + 33554432 + 33554432) {
    k_gemm<<<dim3(256), dim3(512), 0, stream>>>(Xq, W, P);
    k_epi<<<dim3(2048), dim3(256), 0, stream>>>(out, P, scl, bias);
  } else {
    k_gemm_fb<<<dim3(256), dim3(512), 0, stream>>>(Xq, W, scl, bias, out);
  }
}

// Round 16
// 55.333 us; speedup vs baseline: 1.0811x; 1.0194x over previous
//
#include <hip/hip_runtime.h>
#include <hip/hip_bf16.h>

// BQQ dims: P=2, J=32, K=32, M=128, L=16, N=128; B=512; in=kn=4096; out=jm=4096
typedef __attribute__((ext_vector_type(4))) float f32x4;
typedef __attribute__((ext_vector_type(8))) short bf16x8;
typedef __attribute__((ext_vector_type(4))) unsigned int u32x4;

#define GLOBAL_AS __attribute__((address_space(1)))
#define LDS_AS __attribute__((address_space(3)))

static __device__ __forceinline__ unsigned short f2bf(float f) {
  __hip_bfloat16 h = __float2bfloat16(f);
  return __builtin_bit_cast(unsigned short, h);
}
static __device__ __forceinline__ float bf2f(unsigned short u) {
  unsigned int v = ((unsigned int)u) << 16;
  return __builtin_bit_cast(float, v);
}
static __device__ __forceinline__ void load_lds16(const void* g, void* l) {
  __builtin_amdgcn_global_load_lds((GLOBAL_AS void*)g, (LDS_AS void*)l, 16, 0, 0);
}

// ---------------- 1) per-block min/max of input (2M f32), 256 blocks ----------------
__global__ __launch_bounds__(256) void k_minmax_part(const float* __restrict__ x,
                                                     float* __restrict__ part) {
  int tid = blockIdx.x * 256 + threadIdx.x;
  const float4* xv = (const float4*)x;
  float mn = 3.4e38f, mx = -3.4e38f;
#pragma unroll
  for (int rep = 0; rep < 8; ++rep) {
    float4 v = xv[tid + rep * 65536];
    mn = fminf(mn, fminf(fminf(v.x, v.y), fminf(v.z, v.w)));
    mx = fmaxf(mx, fmaxf(fmaxf(v.x, v.y), fmaxf(v.z, v.w)));
  }
#pragma unroll
  for (int o = 32; o > 0; o >>= 1) {
    mn = fminf(mn, __shfl_down(mn, o));
    mx = fmaxf(mx, __shfl_down(mx, o));
  }
  __shared__ float smn[4], smx[4];
  int lane = threadIdx.x & 63, w = threadIdx.x >> 6;
  if (lane == 0) { smn[w] = mn; smx[w] = mx; }
  __syncthreads();
  if (threadIdx.x == 0) {
    mn = fminf(fminf(smn[0], smn[1]), fminf(smn[2], smn[3]));
    mx = fmaxf(fmaxf(smx[0], smx[1]), fmaxf(smx[2], smx[3]));
    part[2 * blockIdx.x] = mn;
    part[2 * blockIdx.x + 1] = mx;
  }
}

// ---------------- 2) fused: blocks 0..1023 = build W (MFMA); 1024..3071 = quantize ----------------
__global__ __launch_bounds__(256) void k_fused(const float* __restrict__ x,
                                               const float* __restrict__ part,
                                               const float* __restrict__ Ysg,
                                               const float* __restrict__ Zsg,
                                               const float* __restrict__ Ysc,
                                               const float* __restrict__ Zsc,
                                               const float* __restrict__ Acoef,
                                               float* __restrict__ scl,
                                               unsigned short* __restrict__ xq,
                                               unsigned short* __restrict__ W) {
  const int t = threadIdx.x;
  if (blockIdx.x < 1024) {
    // ---- build_w (MFMA) ----
    const int jk = blockIdx.x;  // j*32+k
    __shared__ unsigned short Yb[2 * 128 * 24];  // [p*128+m][24] halves; data in [0..16)
    __shared__ unsigned short Zb[128 * 36];      // [n][36] halves; data pl in [0..32)
    __shared__ float B1p[2][128];
    __shared__ float C1[128];
    float cf0[2], cf2[2], cf4[2];
    float Dv;
    {
      float ys0 = Ysc[jk], zs0 = Zsc[jk], ys1 = Ysc[1024 + jk], zs1 = Zsc[1024 + jk];
      const float* A0p = Acoef + (size_t)jk * 4;
      const float* A1p = Acoef + (size_t)(1024 + jk) * 4;
      cf0[0] = A0p[0] * ys0 * zs0; cf0[1] = A1p[0] * ys1 * zs1;
      cf2[0] = A0p[1] * ys0;       cf2[1] = A1p[1] * ys1;
      cf4[0] = A0p[2] * zs0;       cf4[1] = A1p[2] * zs1;
      Dv = A0p[3] + A1p[3];
    }
#pragma unroll
    for (int rep = 0; rep < 4; ++rep) {
      int q = rep * 256 + t;
      int l0 = (q & 3) * 4, m = (q >> 2) & 127, p = q >> 9;
      float4 v = *(const float4*)(Ysg + (size_t)(p * 1024 + jk) * 2048 + m * 16 + l0);
      float s4 = v.x + v.y + v.z + v.w;
      s4 += __shfl_xor(s4, 1);
      s4 += __shfl_xor(s4, 2);
      if ((t & 3) == 0) B1p[p][m] = s4;
      float c0 = cf0[p];
      ushort4 o = make_ushort4(f2bf(c0 * v.x), f2bf(c0 * v.y), f2bf(c0 * v.z), f2bf(c0 * v.w));
      *(ushort4*)&Yb[(p * 128 + m) * 24 + l0] = o;
    }
#pragma unroll
    for (int rep = 0; rep < 4; ++rep) {
      int q = rep * 256 + t;
      int n0 = (q & 31) * 4, l = (q >> 5) & 15, p = q >> 9;
      float4 v = *(const float4*)(Zsg + (size_t)(p * 1024 + jk) * 2048 + l * 128 + n0);
      int pl = p * 16 + l;
      Zb[(n0 + 0) * 36 + pl] = f2bf(v.x);
      Zb[(n0 + 1) * 36 + pl] = f2bf(v.y);
      Zb[(n0 + 2) * 36 + pl] = f2bf(v.z);
      Zb[(n0 + 3) * 36 + pl] = f2bf(v.w);
    }
    __syncthreads();
    if (t < 128) {
      float s0 = 0.f, s1 = 0.f;
#pragma unroll
      for (int l = 0; l < 16; ++l) {
        s0 += bf2f(Zb[t * 36 + l]);
        s1 += bf2f(Zb[t * 36 + 16 + l]);
      }
      C1[t] = cf4[0] * s0 + cf4[1] * s1;
    }
    __syncthreads();
    const int lane = t & 63, wid = t >> 6;
    const int wm = wid >> 1, wn = wid & 1;
    const int grp = lane >> 4;
    bf16x8 af[4], bfr[4];
#pragma unroll
    for (int fm = 0; fm < 4; ++fm) {
      int m = wm * 64 + fm * 16 + (lane & 15);
      af[fm] = *(const bf16x8*)((const char*)Yb + ((grp >> 1) * 128 + m) * 48 + (grp & 1) * 16);
    }
#pragma unroll
    for (int fn = 0; fn < 4; ++fn) {
      int n = wn * 64 + fn * 16 + (lane & 15);
      const char* zp = (const char*)Zb + n * 72 + grp * 16;
      uint2 z0 = *(const uint2*)zp;
      uint2 z1 = *(const uint2*)(zp + 8);
      u32x4 zw; zw[0] = z0.x; zw[1] = z0.y; zw[2] = z1.x; zw[3] = z1.y;
      bfr[fn] = __builtin_bit_cast(bf16x8, zw);
    }
    f32x4 acc[4][4];
#pragma unroll
    for (int fm = 0; fm < 4; ++fm)
#pragma unroll
      for (int fn = 0; fn < 4; ++fn)
        acc[fm][fn] = __builtin_amdgcn_mfma_f32_16x16x32_bf16(af[fm], bfr[fn], (f32x4)(0.f), 0, 0, 0);
    const int j = jk >> 5, k = jk & 31;
    float c1v[4];
#pragma unroll
    for (int fn = 0; fn < 4; ++fn) c1v[fn] = C1[wn * 64 + fn * 16 + (lane & 15)];
#pragma unroll
    for (int fm = 0; fm < 4; ++fm) {
#pragma unroll
      for (int i = 0; i < 4; ++i) {
        int row = wm * 64 + fm * 16 + (grp)*4 + i;
        float b1v = cf2[0] * B1p[0][row] + cf2[1] * B1p[1][row] + Dv;
        size_t rowoff = (size_t)(j * 128 + row) * 4096 + (size_t)(k * 128);
#pragma unroll
        for (int fn = 0; fn < 4; ++fn) {
          int col = wn * 64 + fn * 16 + (lane & 15);
          W[rowoff + col] = f2bf(acc[fm][fn][i] + b1v + c1v[fn]);
        }
      }
    }
  } else {
    // ---- quantize ----
    const int qb = blockIdx.x - 1024;
    float2 v2 = ((const float2*)part)[t];
    float mn = v2.x, mx = v2.y;
#pragma unroll
    for (int o = 32; o > 0; o >>= 1) {
      mn = fminf(mn, __shfl_down(mn, o));
      mx = fmaxf(mx, __shfl_down(mx, o));
    }
    __shared__ float smn2[4], smx2[4], ssc[1];
    int lane = t & 63, w = t >> 6;
    if (lane == 0) { smn2[w] = mn; smx2[w] = mx; }
    __syncthreads();
    if (t == 0) {
      mn = fminf(fminf(smn2[0], smn2[1]), fminf(smn2[2], smn2[3]));
      mx = fmaxf(fmaxf(smx2[0], smx2[1]), fmaxf(smx2[2], smx2[3]));
      ssc[0] = fmaxf((mx - mn) / 254.0f, 1e-8f);
      if (qb == 0) scl[0] = ssc[0];
    }
    __syncthreads();
    const float s = ssc[0];
    int i = qb * 256 + t;
    float4 v = ((const float4*)x)[i];
    float a = fminf(fmaxf(rintf(v.x / s), -127.f), 127.f);
    float b = fminf(fmaxf(rintf(v.y / s), -127.f), 127.f);
    float c = fminf(fmaxf(rintf(v.z / s), -127.f), 127.f);
    float d = fminf(fmaxf(rintf(v.w / s), -127.f), 127.f);
    ((ushort4*)xq)[i] = make_ushort4(f2bf(a), f2bf(b), f2bf(c), f2bf(d));
  }
}

// ---------------- 3) GEMM split-K8: BM=256,BN=256,BK=64; 8 waves 2x4, wave 128x64 ----------------
// R12 structure (best measured): per K-tile {stage A(nxt); vmcnt(4); barrier;
// [ds_read ks0 + stage B(nxt); setprio MFMA x32]; [ds_read ks1; setprio MFMA x32];
// barrier}. Last iter: NO dummy re-stage; full vmcnt(0) drain instead (saves 16MB
// of likely-L2-evicted kt=0 re-reads across the dispatch).
__global__ __launch_bounds__(512) void k_gemm(const unsigned short* __restrict__ Xq,
                                              const unsigned short* __restrict__ W,
                                              unsigned short* __restrict__ P) {
  __shared__ unsigned short Al[2][256 * 64];  // 2 x 32KB, 128B rows, XOR swz
  __shared__ unsigned short Bl[2][256 * 64];  // 2 x 32KB
  const int t = threadIdx.x, lane = t & 63, wid = t >> 6;  // wid 0..7
  const int wg = (blockIdx.x & 7) * 32 + (blockIdx.x >> 3);  // bijective, 256%8==0
  const int sk = wg >> 5;        // 0..7 == XCD id -> W K-panel 4MB = its L2
  const int bm = (wg >> 4) & 1;  // 0..1
  const int bn = wg & 15;        // 0..15
  const int wm = wid >> 2, wn = wid & 3;  // wave tile 128x64 (2x4 waves)
  const int kbase = sk * 512;
  f32x4 acc[8][4];
#pragma unroll
  for (int a = 0; a < 8; ++a)
#pragma unroll
    for (int b = 0; b < 4; ++b) acc[a][b] = (f32x4)(0.f);

  const int lr = lane >> 3;         // row-in-chunk 0..7
  const int lcb = (lane & 7) * 16;  // byte col in 128B row

  auto STAGE_A = [&](int buf, int kt) {
    const int k0 = kbase + kt * 64;
#pragma unroll
    for (int c = 0; c < 4; ++c) {
      int chunk = wid * 4 + c;
      int r = chunk * 8 + lr;
      int colb = lcb ^ ((r & 7) << 4);
      load_lds16(Xq + ((size_t)(bm * 256 + r) << 12) + k0 + (colb >> 1), &Al[buf][chunk * 512]);
    }
  };
  auto STAGE_B = [&](int buf, int kt) {
    const int k0 = kbase + kt * 64;
#pragma unroll
    for (int c = 0; c < 4; ++c) {
      int chunk = wid * 4 + c;
      int r = chunk * 8 + lr;
      int colb = lcb ^ ((r & 7) << 4);
      load_lds16(W + ((size_t)(bn * 256 + r) << 12) + k0 + (colb >> 1), &Bl[buf][chunk * 512]);
    }
  };

  // prologue: fill buf0 (8 loads/wave outstanding)
  STAGE_A(0, 0);
  STAGE_B(0, 0);
  for (int it = 0; it < 8; ++it) {
    const int cur = it & 1, nxt = cur ^ 1;
    const int ktn = it + 1;
    // ---- phase 0: issue next A, gate on current tile landed ----
    if (it < 7) {
      STAGE_A(nxt, ktn);
      __builtin_amdgcn_sched_barrier(0);
      asm volatile("s_waitcnt vmcnt(4)" ::: "memory");  // tile it landed; 4 in flight
      __builtin_amdgcn_sched_barrier(0);
    } else {
      __builtin_amdgcn_sched_barrier(0);
      asm volatile("s_waitcnt vmcnt(0)" ::: "memory");  // final tile: full drain
      __builtin_amdgcn_sched_barrier(0);
    }
    __builtin_amdgcn_s_barrier();                       // buf[cur] ready for all waves
    __builtin_amdgcn_sched_barrier(0);
    // ---- phase 1: ds_read ks0 + issue next B, then MFMA cluster ----
    {
      bf16x8 af[8], bfr[4];
#pragma unroll
      for (int fm = 0; fm < 8; ++fm) {
        int r = wm * 128 + fm * 16 + (lane & 15);
        int colb = (((lane >> 4) * 16)) ^ ((r & 7) << 4);
        af[fm] = *(const bf16x8*)((const char*)&Al[cur][0] + r * 128 + colb);
      }
#pragma unroll
      for (int fn = 0; fn < 4; ++fn) {
        int r = wn * 64 + fn * 16 + (lane & 15);
        int colb = (((lane >> 4) * 16)) ^ ((r & 7) << 4);
        bfr[fn] = *(const bf16x8*)((const char*)&Bl[cur][0] + r * 128 + colb);
      }
      if (it < 7) STAGE_B(nxt, ktn);  // overlaps ds_read latency; outstanding -> 8
      __builtin_amdgcn_sched_barrier(0);
      __builtin_amdgcn_s_setprio(1);
#pragma unroll
      for (int fm = 0; fm < 8; ++fm)
#pragma unroll
        for (int fn = 0; fn < 4; ++fn)
          acc[fm][fn] = __builtin_amdgcn_mfma_f32_16x16x32_bf16(af[fm], bfr[fn], acc[fm][fn], 0, 0, 0);
      __builtin_amdgcn_s_setprio(0);
      __builtin_amdgcn_sched_barrier(0);
    }
    // ---- phase 2: ds_read ks1, MFMA cluster ----
    {
      bf16x8 af[8], bfr[4];
#pragma unroll
      for (int fm = 0; fm < 8; ++fm) {
        int r = wm * 128 + fm * 16 + (lane & 15);
        int colb = (64 + ((lane >> 4) * 16)) ^ ((r & 7) << 4);
        af[fm] = *(const bf16x8*)((const char*)&Al[cur][0] + r * 128 + colb);
      }
#pragma unroll
      for (int fn = 0; fn < 4; ++fn) {
        int r = wn * 64 + fn * 16 + (lane & 15);
        int colb = (64 + ((lane >> 4) * 16)) ^ ((r & 7) << 4);
        bfr[fn] = *(const bf16x8*)((const char*)&Bl[cur][0] + r * 128 + colb);
      }
      __builtin_amdgcn_sched_barrier(0);
      __builtin_amdgcn_s_setprio(1);
#pragma unroll
      for (int fm = 0; fm < 8; ++fm)
#pragma unroll
        for (int fn = 0; fn < 4; ++fn)
          acc[fm][fn] = __builtin_amdgcn_mfma_f32_16x16x32_bf16(af[fm], bfr[fn], acc[fm][fn], 0, 0, 0);
      __builtin_amdgcn_s_setprio(0);
      __builtin_amdgcn_sched_barrier(0);
    }
    __builtin_amdgcn_s_barrier();  // reads of cur done before next iter overwrites
  }

  // register-native coalesced bf16 partial store (512B contiguous per inst)
  unsigned short* Pk = P + (size_t)sk * 2097152;
  const int blkL = bm * 16 + bn;  // 0..31
#pragma unroll
  for (int fm = 0; fm < 8; ++fm) {
#pragma unroll
    for (int fn = 0; fn < 4; ++fn) {
      int idx = (((blkL * 8 + wid) * 32 + fm * 4 + fn) * 64) + lane;
      ushort4 o = make_ushort4(f2bf(acc[fm][fn][0]), f2bf(acc[fm][fn][1]),
                               f2bf(acc[fm][fn][2]), f2bf(acc[fm][fn][3]));
      ((ushort4*)Pk)[idx] = o;
    }
  }
}

// ---------------- 4) epilogue: out = (sum of 8 native-layout partials) * s + bias ----------------
__global__ __launch_bounds__(256) void k_epi(float* __restrict__ out,
                                             const unsigned short* __restrict__ P,
                                             const float* __restrict__ scl,
                                             const float* __restrict__ bias) {
  int g = blockIdx.x * 256 + threadIdx.x;  // 524288 threads, 4 elems each
  const int lane = g & 63;
  const int ff = (g >> 6) & 31;
  const int fn = ff & 3, fm = ff >> 2;
  const int wid = (g >> 11) & 7;
  const int blkL = g >> 14;  // 0..31
  const int bm = blkL >> 4, bn = blkL & 15;
  const int wm = wid >> 2, wn = wid & 3;
  const int row0 = bm * 256 + wm * 128 + fm * 16 + ((lane >> 4) << 2);
  const int col = bn * 256 + wn * 64 + fn * 16 + (lane & 15);
  const float s = scl[0];
  const float bv = bias[col];
  float sum[4] = {0.f, 0.f, 0.f, 0.f};
#pragma unroll
  for (int k = 0; k < 8; ++k) {
    ushort4 p = ((const ushort4*)(P + (size_t)k * 2097152))[g];
    sum[0] += bf2f(p.x); sum[1] += bf2f(p.y); sum[2] += bf2f(p.z); sum[3] += bf2f(p.w);
  }
#pragma unroll
  for (int i = 0; i < 4; ++i) out[(size_t)(row0 + i) * 4096 + col] = sum[i] * s + bv;
}

// ---------------- fallback GEMM (used if ws too small for partials) ----------------
__global__ __launch_bounds__(512) void k_gemm_fb(const unsigned short* __restrict__ Xq,
                                                 const unsigned short* __restrict__ W,
                                                 const float* __restrict__ scl,
                                                 const float* __restrict__ bias,
                                                 float* __restrict__ out) {
  __shared__ unsigned short Al[4][128 * 64];
  __shared__ unsigned short Bl[4][64 * 64];
  const int t = threadIdx.x, lane = t & 63, wid = t >> 6;
  const int wg = (blockIdx.x & 7) * 32 + (blockIdx.x >> 3);
  const int bm = wg & 3;
  const int bn = wg >> 2;
  const int wm = wid >> 1, wn = wid & 1;
  f32x4 acc[2][2];
#pragma unroll
  for (int a = 0; a < 2; ++a)
#pragma unroll
    for (int b = 0; b < 2; ++b) acc[a][b] = (f32x4)(0.f);
  const int lr = lane >> 3;
  const int lcb = (lane & 7) * 16;
  auto STAGE = [&](int buf, int kt) {
    const int k0 = kt * 64;
#pragma unroll
    for (int c = 0; c < 2; ++c) {
      int chunk = wid * 2 + c;
      int r = chunk * 8 + lr;
      int colb = lcb ^ ((r & 7) << 4);
      load_lds16(Xq + ((size_t)(bm * 128 + r) << 12) + k0 + (colb >> 1), &Al[buf][chunk * 512]);
    }
    {
      int r = wid * 8 + lr;
      int colb = lcb ^ ((r & 7) << 4);
      load_lds16(W + ((size_t)(bn * 64 + r) << 12) + k0 + (colb >> 1), &Bl[buf][wid * 512]);
    }
  };
  auto COMPUTE = [&](int buf) {
#pragma unroll
    for (int ks = 0; ks < 2; ++ks) {
      bf16x8 af[2], bfr[2];
#pragma unroll
      for (int fm = 0; fm < 2; ++fm) {
        int r = wm * 32 + fm * 16 + (lane & 15);
        int colb = (ks * 64 + ((lane >> 4) * 16)) ^ ((r & 7) << 4);
        af[fm] = *(const bf16x8*)((const char*)&Al[buf][0] + r * 128 + colb);
      }
#pragma unroll
      for (int fn = 0; fn < 2; ++fn) {
        int r = wn * 32 + fn * 16 + (lane & 15);
        int colb = (ks * 64 + ((lane >> 4) * 16)) ^ ((r & 7) << 4);
        bfr[fn] = *(const bf16x8*)((const char*)&Bl[buf][0] + r * 128 + colb);
      }
#pragma unroll
      for (int fm = 0; fm < 2; ++fm)
#pragma unroll
        for (int fn = 0; fn < 2; ++fn)
          acc[fm][fn] = __builtin_amdgcn_mfma_f32_16x16x32_bf16(af[fm], bfr[fn], acc[fm][fn], 0, 0, 0);
    }
  };
  STAGE(0, 0); STAGE(1, 1); STAGE(2, 2);
  for (int t64 = 0; t64 < 64; ++t64) {
    STAGE((t64 + 3) & 3, (t64 + 3) & 63);
    __builtin_amdgcn_sched_barrier(0);
    asm volatile("s_waitcnt vmcnt(9)" ::: "memory");
    __builtin_amdgcn_sched_barrier(0);
    __builtin_amdgcn_s_barrier();
    __builtin_amdgcn_sched_barrier(0);
    COMPUTE(t64 & 3);
    __builtin_amdgcn_sched_barrier(0);
    __builtin_amdgcn_s_barrier();
  }
  const float s = scl[0];
#pragma unroll
  for (int fn = 0; fn < 2; ++fn) {
    int col = bn * 64 + wn * 32 + fn * 16 + (lane & 15);
    float bv = bias[col];
#pragma unroll
    for (int fm = 0; fm < 2; ++fm) {
#pragma unroll
      for (int i = 0; i < 4; ++i) {
        int row = bm * 128 + wm * 32 + fm * 16 + (lane >> 4) * 4 + i;
        out[(size_t)row * 4096 + col] = acc[fm][fn][i] * s + bv;
      }
    }
  }
}

extern "C" void kernel_launch(void* const* d_in, const int* in_sizes, int n_in,
                              void* d_out, int out_size, void* d_ws, size_t ws_size,
                              hipStream_t stream) {
  const float* x    = (const float*)d_in[0];  // (1,512,4096)
  const float* Ysg  = (const float*)d_in[1];  // (2,32,32,128,16)
  const float* Zsg  = (const float*)d_in[2];  // (2,32,32,16,128)
  const float* Ysc  = (const float*)d_in[3];  // (2,32,32)
  const float* Zsc  = (const float*)d_in[4];  // (2,32,32)
  const float* A    = (const float*)d_in[5];  // (2,32,32,4)
  const float* bias = (const float*)d_in[6];  // (4096,)
  float* out = (float*)d_out;

  char* ws = (char*)d_ws;
  float* scl  = (float*)ws;                  // [0] act_scale
  float* part = (float*)(ws + 256);          // 512 f32 partials
  unsigned short* Xq = (unsigned short*)(ws + 65536);                    // 4MB bf16
  unsigned short* W  = (unsigned short*)(ws + 65536 + (size_t)4194304);  // 32MB bf16
  unsigned short* P  = (unsigned short*)(ws + 65536 + (size_t)4194304 + (size_t)33554432);  // 32MB bf16 partials (8 slices)

  k_minmax_part<<<dim3(256), dim3(256), 0, stream>>>(x, part);
  k_fused<<<dim3(3072), dim3(256), 0, stream>>>(x, part, Ysg, Zsg, Ysc, Zsc, A, scl, Xq, W);
  if (ws_size >= (size_t)65536 + 4194304 + 33554432 + 33554432) {
    k_gemm<<<dim3(256), dim3(512), 0, stream>>>(Xq, W, P);
    k_epi<<<dim3(2048), dim3(256), 0, stream>>>(out, P, scl, bias);
  } else {
    k_gemm_fb<<<dim3(256), dim3(512), 0, stream>>>(Xq, W, scl, bias, out);
  }
}

// Round 17
// 54.042 us; speedup vs baseline: 1.1069x; 1.0239x over previous
//
#include <hip/hip_runtime.h>
#include <hip/hip_bf16.h>

// BQQ dims: P=2, J=32, K=32, M=128, L=16, N=128; B=512; in=kn=4096; out=jm=4096
typedef __attribute__((ext_vector_type(4))) float f32x4;
typedef __attribute__((ext_vector_type(8))) short bf16x8;
typedef __attribute__((ext_vector_type(4))) unsigned int u32x4;

#define GLOBAL_AS __attribute__((address_space(1)))
#define LDS_AS __attribute__((address_space(3)))

static __device__ __forceinline__ unsigned short f2bf(float f) {
  __hip_bfloat16 h = __float2bfloat16(f);
  return __builtin_bit_cast(unsigned short, h);
}
static __device__ __forceinline__ float bf2f(unsigned short u) {
  unsigned int v = ((unsigned int)u) << 16;
  return __builtin_bit_cast(float, v);
}
static __device__ __forceinline__ void load_lds16(const void* g, void* l) {
  __builtin_amdgcn_global_load_lds((GLOBAL_AS void*)g, (LDS_AS void*)l, 16, 0, 0);
}

// ---------------- 1) per-block min/max of input (2M f32), 256 blocks ----------------
__global__ __launch_bounds__(256) void k_minmax_part(const float* __restrict__ x,
                                                     float* __restrict__ part) {
  int tid = blockIdx.x * 256 + threadIdx.x;
  const float4* xv = (const float4*)x;
  float mn = 3.4e38f, mx = -3.4e38f;
#pragma unroll
  for (int rep = 0; rep < 8; ++rep) {
    float4 v = xv[tid + rep * 65536];
    mn = fminf(mn, fminf(fminf(v.x, v.y), fminf(v.z, v.w)));
    mx = fmaxf(mx, fmaxf(fmaxf(v.x, v.y), fmaxf(v.z, v.w)));
  }
#pragma unroll
  for (int o = 32; o > 0; o >>= 1) {
    mn = fminf(mn, __shfl_down(mn, o));
    mx = fmaxf(mx, __shfl_down(mx, o));
  }
  __shared__ float smn[4], smx[4];
  int lane = threadIdx.x & 63, w = threadIdx.x >> 6;
  if (lane == 0) { smn[w] = mn; smx[w] = mx; }
  __syncthreads();
  if (threadIdx.x == 0) {
    mn = fminf(fminf(smn[0], smn[1]), fminf(smn[2], smn[3]));
    mx = fmaxf(fmaxf(smx[0], smx[1]), fmaxf(smx[2], smx[3]));
    part[2 * blockIdx.x] = mn;
    part[2 * blockIdx.x + 1] = mx;
  }
}

// ---------------- 2) fused: blocks 0..1023 = build W (MFMA); 1024..3071 = quantize ----------------
__global__ __launch_bounds__(256) void k_fused(const float* __restrict__ x,
                                               const float* __restrict__ part,
                                               const float* __restrict__ Ysg,
                                               const float* __restrict__ Zsg,
                                               const float* __restrict__ Ysc,
                                               const float* __restrict__ Zsc,
                                               const float* __restrict__ Acoef,
                                               float* __restrict__ scl,
                                               unsigned short* __restrict__ xq,
                                               unsigned short* __restrict__ W) {
  const int t = threadIdx.x;
  if (blockIdx.x < 1024) {
    // ---- build_w (MFMA) ----
    const int jk = blockIdx.x;  // j*32+k
    __shared__ unsigned short Yb[2 * 128 * 24];  // [p*128+m][24] halves; data in [0..16)
    __shared__ unsigned short Zb[128 * 36];      // [n][36] halves; data pl in [0..32)
    __shared__ float B1p[2][128];
    __shared__ float C1[128];
    float cf0[2], cf2[2], cf4[2];
    float Dv;
    {
      float ys0 = Ysc[jk], zs0 = Zsc[jk], ys1 = Ysc[1024 + jk], zs1 = Zsc[1024 + jk];
      const float* A0p = Acoef + (size_t)jk * 4;
      const float* A1p = Acoef + (size_t)(1024 + jk) * 4;
      cf0[0] = A0p[0] * ys0 * zs0; cf0[1] = A1p[0] * ys1 * zs1;
      cf2[0] = A0p[1] * ys0;       cf2[1] = A1p[1] * ys1;
      cf4[0] = A0p[2] * zs0;       cf4[1] = A1p[2] * zs1;
      Dv = A0p[3] + A1p[3];
    }
#pragma unroll
    for (int rep = 0; rep < 4; ++rep) {
      int q = rep * 256 + t;
      int l0 = (q & 3) * 4, m = (q >> 2) & 127, p = q >> 9;
      float4 v = *(const float4*)(Ysg + (size_t)(p * 1024 + jk) * 2048 + m * 16 + l0);
      float s4 = v.x + v.y + v.z + v.w;
      s4 += __shfl_xor(s4, 1);
      s4 += __shfl_xor(s4, 2);
      if ((t & 3) == 0) B1p[p][m] = s4;
      float c0 = cf0[p];
      ushort4 o = make_ushort4(f2bf(c0 * v.x), f2bf(c0 * v.y), f2bf(c0 * v.z), f2bf(c0 * v.w));
      *(ushort4*)&Yb[(p * 128 + m) * 24 + l0] = o;
    }
#pragma unroll
    for (int rep = 0; rep < 4; ++rep) {
      int q = rep * 256 + t;
      int n0 = (q & 31) * 4, l = (q >> 5) & 15, p = q >> 9;
      float4 v = *(const float4*)(Zsg + (size_t)(p * 1024 + jk) * 2048 + l * 128 + n0);
      int pl = p * 16 + l;
      Zb[(n0 + 0) * 36 + pl] = f2bf(v.x);
      Zb[(n0 + 1) * 36 + pl] = f2bf(v.y);
      Zb[(n0 + 2) * 36 + pl] = f2bf(v.z);
      Zb[(n0 + 3) * 36 + pl] = f2bf(v.w);
    }
    __syncthreads();
    if (t < 128) {
      float s0 = 0.f, s1 = 0.f;
#pragma unroll
      for (int l = 0; l < 16; ++l) {
        s0 += bf2f(Zb[t * 36 + l]);
        s1 += bf2f(Zb[t * 36 + 16 + l]);
      }
      C1[t] = cf4[0] * s0 + cf4[1] * s1;
    }
    __syncthreads();
    const int lane = t & 63, wid = t >> 6;
    const int wm = wid >> 1, wn = wid & 1;
    const int grp = lane >> 4;
    bf16x8 af[4], bfr[4];
#pragma unroll
    for (int fm = 0; fm < 4; ++fm) {
      int m = wm * 64 + fm * 16 + (lane & 15);
      af[fm] = *(const bf16x8*)((const char*)Yb + ((grp >> 1) * 128 + m) * 48 + (grp & 1) * 16);
    }
#pragma unroll
    for (int fn = 0; fn < 4; ++fn) {
      int n = wn * 64 + fn * 16 + (lane & 15);
      const char* zp = (const char*)Zb + n * 72 + grp * 16;
      uint2 z0 = *(const uint2*)zp;
      uint2 z1 = *(const uint2*)(zp + 8);
      u32x4 zw; zw[0] = z0.x; zw[1] = z0.y; zw[2] = z1.x; zw[3] = z1.y;
      bfr[fn] = __builtin_bit_cast(bf16x8, zw);
    }
    f32x4 acc[4][4];
#pragma unroll
    for (int fm = 0; fm < 4; ++fm)
#pragma unroll
      for (int fn = 0; fn < 4; ++fn)
        acc[fm][fn] = __builtin_amdgcn_mfma_f32_16x16x32_bf16(af[fm], bfr[fn], (f32x4)(0.f), 0, 0, 0);
    const int j = jk >> 5, k = jk & 31;
    float c1v[4];
#pragma unroll
    for (int fn = 0; fn < 4; ++fn) c1v[fn] = C1[wn * 64 + fn * 16 + (lane & 15)];
#pragma unroll
    for (int fm = 0; fm < 4; ++fm) {
#pragma unroll
      for (int i = 0; i < 4; ++i) {
        int row = wm * 64 + fm * 16 + (grp)*4 + i;
        float b1v = cf2[0] * B1p[0][row] + cf2[1] * B1p[1][row] + Dv;
        size_t rowoff = (size_t)(j * 128 + row) * 4096 + (size_t)(k * 128);
#pragma unroll
        for (int fn = 0; fn < 4; ++fn) {
          int col = wn * 64 + fn * 16 + (lane & 15);
          W[rowoff + col] = f2bf(acc[fm][fn][i] + b1v + c1v[fn]);
        }
      }
    }
  } else {
    // ---- quantize ----
    const int qb = blockIdx.x - 1024;
    float2 v2 = ((const float2*)part)[t];
    float mn = v2.x, mx = v2.y;
#pragma unroll
    for (int o = 32; o > 0; o >>= 1) {
      mn = fminf(mn, __shfl_down(mn, o));
      mx = fmaxf(mx, __shfl_down(mx, o));
    }
    __shared__ float smn2[4], smx2[4], ssc[1];
    int lane = t & 63, w = t >> 6;
    if (lane == 0) { smn2[w] = mn; smx2[w] = mx; }
    __syncthreads();
    if (t == 0) {
      mn = fminf(fminf(smn2[0], smn2[1]), fminf(smn2[2], smn2[3]));
      mx = fmaxf(fmaxf(smx2[0], smx2[1]), fmaxf(smx2[2], smx2[3]));
      ssc[0] = fmaxf((mx - mn) / 254.0f, 1e-8f);
      if (qb == 0) scl[0] = ssc[0];
    }
    __syncthreads();
    const float s = ssc[0];
    int i = qb * 256 + t;
    float4 v = ((const float4*)x)[i];
    float a = fminf(fmaxf(rintf(v.x / s), -127.f), 127.f);
    float b = fminf(fmaxf(rintf(v.y / s), -127.f), 127.f);
    float c = fminf(fmaxf(rintf(v.z / s), -127.f), 127.f);
    float d = fminf(fmaxf(rintf(v.w / s), -127.f), 127.f);
    ((ushort4*)xq)[i] = make_ushort4(f2bf(a), f2bf(b), f2bf(c), f2bf(d));
  }
}

// ---------------- 3) GEMM split-K8: BM=256,BN=256,BK=64; 8 waves 2x4, wave 128x64 ----------------
// R12 structure (best measured, 53.8us): per K-tile
//   {stage A(nxt); vmcnt(4); barrier;
//    [ds_read ks0 + stage B(nxt); setprio MFMA x32];
//    [ds_read ks1; setprio MFMA x32]; barrier}.
// it=7 restages kt=0 (dummy, never read) to keep vmcnt arithmetic uniform.
__global__ __launch_bounds__(512) void k_gemm(const unsigned short* __restrict__ Xq,
                                              const unsigned short* __restrict__ W,
                                              unsigned short* __restrict__ P) {
  __shared__ unsigned short Al[2][256 * 64];  // 2 x 32KB
  __shared__ unsigned short Bl[2][256 * 64];  // 2 x 32KB
  const int t = threadIdx.x, lane = t & 63, wid = t >> 6;  // wid 0..7
  const int wg = (blockIdx.x & 7) * 32 + (blockIdx.x >> 3);  // bijective, 256%8==0
  const int sk = wg >> 5;        // 0..7 == XCD id -> W K-panel 4MB = its L2
  const int bm = (wg >> 4) & 1;  // 0..1
  const int bn = wg & 15;        // 0..15
  const int wm = wid >> 2, wn = wid & 3;  // wave tile 128x64 (2x4 waves)
  const int kbase = sk * 512;
  f32x4 acc[8][4];
#pragma unroll
  for (int a = 0; a < 8; ++a)
#pragma unroll
    for (int b = 0; b < 4; ++b) acc[a][b] = (f32x4)(0.f);

  const int lr = lane >> 3;         // row-in-chunk 0..7
  const int lcb = (lane & 7) * 16;  // byte col in 128B row

  auto STAGE_A = [&](int buf, int kt) {
    const int k0 = kbase + kt * 64;
#pragma unroll
    for (int c = 0; c < 4; ++c) {
      int chunk = wid * 4 + c;
      int r = chunk * 8 + lr;
      int colb = lcb ^ ((r & 7) << 4);
      load_lds16(Xq + ((size_t)(bm * 256 + r) << 12) + k0 + (colb >> 1), &Al[buf][chunk * 512]);
    }
  };
  auto STAGE_B = [&](int buf, int kt) {
    const int k0 = kbase + kt * 64;
#pragma unroll
    for (int c = 0; c < 4; ++c) {
      int chunk = wid * 4 + c;
      int r = chunk * 8 + lr;
      int colb = lcb ^ ((r & 7) << 4);
      load_lds16(W + ((size_t)(bn * 256 + r) << 12) + k0 + (colb >> 1), &Bl[buf][chunk * 512]);
    }
  };

  // prologue: fill buf0 (8 loads/wave outstanding)
  STAGE_A(0, 0);
  STAGE_B(0, 0);
  for (int it = 0; it < 8; ++it) {
    const int cur = it & 1, nxt = cur ^ 1;
    const int ktn = (it + 1) & 7;  // it=7 restages kt=0 (dummy, never read)
    // ---- phase 0: issue next A, gate on prev tile landed ----
    STAGE_A(nxt, ktn);
    __builtin_amdgcn_sched_barrier(0);
    asm volatile("s_waitcnt vmcnt(4)" ::: "memory");  // prev 8 done; new 4 in flight
    __builtin_amdgcn_sched_barrier(0);
    __builtin_amdgcn_s_barrier();                     // buf[cur] ready for all waves
    __builtin_amdgcn_sched_barrier(0);
    // ---- phase 1: ds_read ks0 + issue next B, then MFMA cluster ----
    {
      bf16x8 af[8], bfr[4];
#pragma unroll
      for (int fm = 0; fm < 8; ++fm) {
        int r = wm * 128 + fm * 16 + (lane & 15);
        int colb = (((lane >> 4) * 16)) ^ ((r & 7) << 4);
        af[fm] = *(const bf16x8*)((const char*)&Al[cur][0] + r * 128 + colb);
      }
#pragma unroll
      for (int fn = 0; fn < 4; ++fn) {
        int r = wn * 64 + fn * 16 + (lane & 15);
        int colb = (((lane >> 4) * 16)) ^ ((r & 7) << 4);
        bfr[fn] = *(const bf16x8*)((const char*)&Bl[cur][0] + r * 128 + colb);
      }
      STAGE_B(nxt, ktn);  // overlaps with ds_read latency; outstanding -> 8
      __builtin_amdgcn_sched_barrier(0);
      __builtin_amdgcn_s_setprio(1);
#pragma unroll
      for (int fm = 0; fm < 8; ++fm)
#pragma unroll
        for (int fn = 0; fn < 4; ++fn)
          acc[fm][fn] = __builtin_amdgcn_mfma_f32_16x16x32_bf16(af[fm], bfr[fn], acc[fm][fn], 0, 0, 0);
      __builtin_amdgcn_s_setprio(0);
      __builtin_amdgcn_sched_barrier(0);
    }
    // ---- phase 2: ds_read ks1, MFMA cluster ----
    {
      bf16x8 af[8], bfr[4];
#pragma unroll
      for (int fm = 0; fm < 8; ++fm) {
        int r = wm * 128 + fm * 16 + (lane & 15);
        int colb = (64 + ((lane >> 4) * 16)) ^ ((r & 7) << 4);
        af[fm] = *(const bf16x8*)((const char*)&Al[cur][0] + r * 128 + colb);
      }
#pragma unroll
      for (int fn = 0; fn < 4; ++fn) {
        int r = wn * 64 + fn * 16 + (lane & 15);
        int colb = (64 + ((lane >> 4) * 16)) ^ ((r & 7) << 4);
        bfr[fn] = *(const bf16x8*)((const char*)&Bl[cur][0] + r * 128 + colb);
      }
      __builtin_amdgcn_sched_barrier(0);
      __builtin_amdgcn_s_setprio(1);
#pragma unroll
      for (int fm = 0; fm < 8; ++fm)
#pragma unroll
        for (int fn = 0; fn < 4; ++fn)
          acc[fm][fn] = __builtin_amdgcn_mfma_f32_16x16x32_bf16(af[fm], bfr[fn], acc[fm][fn], 0, 0, 0);
      __builtin_amdgcn_s_setprio(0);
      __builtin_amdgcn_sched_barrier(0);
    }
    __builtin_amdgcn_s_barrier();  // reads of cur done before next iter overwrites
  }

  // register-native coalesced bf16 partial store (512B contiguous per inst)
  unsigned short* Pk = P + (size_t)sk * 2097152;
  const int blkL = bm * 16 + bn;  // 0..31
#pragma unroll
  for (int fm = 0; fm < 8; ++fm) {
#pragma unroll
    for (int fn = 0; fn < 4; ++fn) {
      int idx = (((blkL * 8 + wid) * 32 + fm * 4 + fn) * 64) + lane;
      ushort4 o = make_ushort4(f2bf(acc[fm][fn][0]), f2bf(acc[fm][fn][1]),
                               f2bf(acc[fm][fn][2]), f2bf(acc[fm][fn][3]));
      ((ushort4*)Pk)[idx] = o;
    }
  }
}

// ---------------- 4) epilogue: out = (sum of 8 native-layout partials) * s + bias ----------------
__global__ __launch_bounds__(256) void k_epi(float* __restrict__ out,
                                             const unsigned short* __restrict__ P,
                                             const float* __restrict__ scl,
                                             const float* __restrict__ bias) {
  int g = blockIdx.x * 256 + threadIdx.x;  // 524288 threads, 4 elems each
  const int lane = g & 63;
  const int ff = (g >> 6) & 31;
  const int fn = ff & 3, fm = ff >> 2;
  const int wid = (g >> 11) & 7;
  const int blkL = g >> 14;  // 0..31
  const int bm = blkL >> 4, bn = blkL & 15;
  const int wm = wid >> 2, wn = wid & 3;
  const int row0 = bm * 256 + wm * 128 + fm * 16 + ((lane >> 4) << 2);
  const int col = bn * 256 + wn * 64 + fn * 16 + (lane & 15);
  const float s = scl[0];
  const float bv = bias[col];
  float sum[4] = {0.f, 0.f, 0.f, 0.f};
#pragma unroll
  for (int k = 0; k < 8; ++k) {
    ushort4 p = ((const ushort4*)(P + (size_t)k * 2097152))[g];
    sum[0] += bf2f(p.x); sum[1] += bf2f(p.y); sum[2] += bf2f(p.z); sum[3] += bf2f(p.w);
  }
#pragma unroll
  for (int i = 0; i < 4; ++i) out[(size_t)(row0 + i) * 4096 + col] = sum[i] * s + bv;
}

// ---------------- fallback GEMM (used if ws too small for partials) ----------------
__global__ __launch_bounds__(512) void k_gemm_fb(const unsigned short* __restrict__ Xq,
                                                 const unsigned short* __restrict__ W,
                                                 const float* __restrict__ scl,
                                                 const float* __restrict__ bias,
                                                 float* __restrict__ out) {
  __shared__ unsigned short Al[4][128 * 64];
  __shared__ unsigned short Bl[4][64 * 64];
  const int t = threadIdx.x, lane = t & 63, wid = t >> 6;
  const int wg = (blockIdx.x & 7) * 32 + (blockIdx.x >> 3);
  const int bm = wg & 3;
  const int bn = wg >> 2;
  const int wm = wid >> 1, wn = wid & 1;
  f32x4 acc[2][2];
#pragma unroll
  for (int a = 0; a < 2; ++a)
#pragma unroll
    for (int b = 0; b < 2; ++b) acc[a][b] = (f32x4)(0.f);
  const int lr = lane >> 3;
  const int lcb = (lane & 7) * 16;
  auto STAGE = [&](int buf, int kt) {
    const int k0 = kt * 64;
#pragma unroll
    for (int c = 0; c < 2; ++c) {
      int chunk = wid * 2 + c;
      int r = chunk * 8 + lr;
      int colb = lcb ^ ((r & 7) << 4);
      load_lds16(Xq + ((size_t)(bm * 128 + r) << 12) + k0 + (colb >> 1), &Al[buf][chunk * 512]);
    }
    {
      int r = wid * 8 + lr;
      int colb = lcb ^ ((r & 7) << 4);
      load_lds16(W + ((size_t)(bn * 64 + r) << 12) + k0 + (colb >> 1), &Bl[buf][wid * 512]);
    }
  };
  auto COMPUTE = [&](int buf) {
#pragma unroll
    for (int ks = 0; ks < 2; ++ks) {
      bf16x8 af[2], bfr[2];
#pragma unroll
      for (int fm = 0; fm < 2; ++fm) {
        int r = wm * 32 + fm * 16 + (lane & 15);
        int colb = (ks * 64 + ((lane >> 4) * 16)) ^ ((r & 7) << 4);
        af[fm] = *(const bf16x8*)((const char*)&Al[buf][0] + r * 128 + colb);
      }
#pragma unroll
      for (int fn = 0; fn < 2; ++fn) {
        int r = wn * 32 + fn * 16 + (lane & 15);
        int colb = (ks * 64 + ((lane >> 4) * 16)) ^ ((r & 7) << 4);
        bfr[fn] = *(const bf16x8*)((const char*)&Bl[buf][0] + r * 128 + colb);
      }
#pragma unroll
      for (int fm = 0; fm < 2; ++fm)
#pragma unroll
        for (int fn = 0; fn < 2; ++fn)
          acc[fm][fn] = __builtin_amdgcn_mfma_f32_16x16x32_bf16(af[fm], bfr[fn], acc[fm][fn], 0, 0, 0);
    }
  };
  STAGE(0, 0); STAGE(1, 1); STAGE(2, 2);
  for (int t64 = 0; t64 < 64; ++t64) {
    STAGE((t64 + 3) & 3, (t64 + 3) & 63);
    __builtin_amdgcn_sched_barrier(0);
    asm volatile("s_waitcnt vmcnt(9)" ::: "memory");
    __builtin_amdgcn_sched_barrier(0);
    __builtin_amdgcn_s_barrier();
    __builtin_amdgcn_sched_barrier(0);
    COMPUTE(t64 & 3);
    __builtin_amdgcn_sched_barrier(0);
    __builtin_amdgcn_s_barrier();
  }
  const float s = scl[0];
#pragma unroll
  for (int fn = 0; fn < 2; ++fn) {
    int col = bn * 64 + wn * 32 + fn * 16 + (lane & 15);
    float bv = bias[col];
#pragma unroll
    for (int fm = 0; fm < 2; ++fm) {
#pragma unroll
      for (int i = 0; i < 4; ++i) {
        int row = bm * 128 + wm * 32 + fm * 16 + (lane >> 4) * 4 + i;
        out[(size_t)row * 4096 + col] = acc[fm][fn][i] * s + bv;
      }
    }
  }
}

extern "C" void kernel_launch(void* const* d_in, const int* in_sizes, int n_in,
                              void* d_out, int out_size, void* d_ws, size_t ws_size,
                              hipStream_t stream) {
  const float* x    = (const float*)d_in[0];  // (1,512,4096)
  const float* Ysg  = (const float*)d_in[1];  // (2,32,32,128,16)
  const float* Zsg  = (const float*)d_in[2];  // (2,32,32,16,128)
  const float* Ysc  = (const float*)d_in[3];  // (2,32,32)
  const float* Zsc  = (const float*)d_in[4];  // (2,32,32)
  const float* A    = (const float*)d_in[5];  // (2,32,32,4)
  const float* bias = (const float*)d_in[6];  // (4096,)
  float* out = (float*)d_out;

  char* ws = (char*)d_ws;
  float* scl  = (float*)ws;                  // [0] act_scale
  float* part = (float*)(ws + 256);          // 512 f32 partials
  unsigned short* Xq = (unsigned short*)(ws + 65536);                    // 4MB bf16
  unsigned short* W  = (unsigned short*)(ws + 65536 + (size_t)4194304);  // 32MB bf16
  unsigned short* P  = (unsigned short*)(ws + 65536 + (size_t)4194304 + (size_t)33554432);  // 32MB bf16 partials (8 slices)

  k_minmax_part<<<dim3(256), dim3(256), 0, stream>>>(x, part);
  k_fused<<<dim3(3072), dim3(256), 0, stream>>>(x, part, Ysg, Zsg, Ysc, Zsc, A, scl, Xq, W);
  if (ws_size >= (size_t)65536 + 4194304 + 33554432 + 33554432) {
    k_gemm<<<dim3(256), dim3(512), 0, stream>>>(Xq, W, P);
    k_epi<<<dim3(2048), dim3(256), 0, stream>>>(out, P, scl, bias);
  } else {
    k_gemm_fb<<<dim3(256), dim3(512), 0, stream>>>(Xq, W, scl, bias, out);
  }
}